// Round 14
// baseline (218.884 us; speedup 1.0000x reference)
//
#include <hip/hip_runtime.h>
#include <hip/hip_bf16.h>
#include <stdint.h>

#define D_MODEL 768
#define HEADS   12
#define DHEAD   64
#define D_FF    3072
#define BB      2
#define SS      2048
#define MTOT    (BB*SS)   // 4096

typedef uint16_t u16;
typedef uint32_t u32;
typedef __attribute__((ext_vector_type(8))) short short8;
typedef __attribute__((ext_vector_type(4))) short short4v;
typedef __attribute__((ext_vector_type(4))) float f32x4;
typedef __attribute__((ext_vector_type(16))) float f32x16;
typedef __attribute__((ext_vector_type(2))) unsigned uint2v;

__device__ __forceinline__ u16 f2bf(float f) {
    union { float f; u32 u; } v; v.f = f;
    u32 r = v.u + 0x7fffu + ((v.u >> 16) & 1u);
    return (u16)(r >> 16);
}

__device__ __forceinline__ float bf2f(u16 u) {
    union { u32 u; float f; } v; v.u = ((u32)u) << 16;
    return v.f;
}

// raw v_exp_f32 (2^x): scores bounded |x|<~16, no OCML range-check expansion
__device__ __forceinline__ float exp2_fast(float x) {
#if __has_builtin(__builtin_amdgcn_exp2f)
    return __builtin_amdgcn_exp2f(x);
#else
    return exp2f(x);
#endif
}

// packed bf16 convert: dst = {bf16(a) lo, bf16(b) hi}  (T12 recipe)
__device__ __forceinline__ u32 cvtpk(float a, float b) {
    u32 r;
    asm("v_cvt_pk_bf16_f32 %0, %1, %2" : "=v"(r) : "v"(a), "v"(b));
    return r;
}

// half-wave exchange: a' = [a.row0, b.row0], b' = [a.row1, b.row1]
__device__ __forceinline__ void plswap(u32& a, u32& b, int hi) {
#if __has_builtin(__builtin_amdgcn_permlane32_swap)
    uint2v r = __builtin_amdgcn_permlane32_swap(a, b, false, false);
    a = r[0]; b = r[1];
#else
    u32 ax = (u32)__shfl_xor((int)a, 32), bx = (u32)__shfl_xor((int)b, 32);
    u32 na = hi ? bx : a, nb = hi ? b : ax;
    a = na; b = nb;
#endif
}

__device__ __forceinline__ void gload16(const void* g, void* l) {
    __builtin_amdgcn_global_load_lds(
        (const __attribute__((address_space(1))) u32*)g,
        (__attribute__((address_space(3))) u32*)l, 16, 0, 0);
}

#define MFMA16(a, b, c) __builtin_amdgcn_mfma_f32_16x16x32_bf16((a), (b), (c), 0, 0, 0)
#define MFMA32(a, b, c) __builtin_amdgcn_mfma_f32_32x32x16_bf16((a), (b), (c), 0, 0, 0)

__device__ __forceinline__ float gelu_tanh_f(float x) {
    float x3 = x * x * x;
    return 0.5f * x * (1.0f + tanhf(0.7978845608028654f * (x + 0.044715f * x3)));
}

// ---------------- weight transpose + cast: W[R][C] fp32 -> Wt[C][R] bf16 ----
__global__ __launch_bounds__(256)
void transpose_cast(const float* __restrict__ W, u16* __restrict__ Wt, int R, int C) {
    __shared__ float tile[32][33];
    int bx = blockIdx.x, by = blockIdx.y;
    int x = threadIdx.x & 31, y0 = threadIdx.x >> 5;
#pragma unroll
    for (int i = 0; i < 4; ++i) {
        int y = y0 + i * 8;
        tile[y][x] = W[(size_t)(by * 32 + y) * C + bx * 32 + x];
    }
    __syncthreads();
#pragma unroll
    for (int i = 0; i < 4; ++i) {
        int y = y0 + i * 8;
        Wt[(size_t)(bx * 32 + y) * R + by * 32 + x] = f2bf(tile[x][y]);
    }
}

// batched 768x768 transpose: z selects among 4 weight matrices
__global__ __launch_bounds__(256)
void transpose_cast4(const float* __restrict__ W0, const float* __restrict__ W1,
                     const float* __restrict__ W2, const float* __restrict__ W3,
                     u16* __restrict__ T0, u16* __restrict__ T1,
                     u16* __restrict__ T2, u16* __restrict__ T3) {
    const int z = blockIdx.z;
    const float* W = z == 0 ? W0 : z == 1 ? W1 : z == 2 ? W2 : W3;
    u16*         T = z == 0 ? T0 : z == 1 ? T1 : z == 2 ? T2 : T3;
    __shared__ float tile[32][33];
    int bx = blockIdx.x, by = blockIdx.y;
    int x = threadIdx.x & 31, y0 = threadIdx.x >> 5;
#pragma unroll
    for (int i = 0; i < 4; ++i) {
        int y = y0 + i * 8;
        tile[y][x] = W[(size_t)(by * 32 + y) * 768 + bx * 32 + x];
    }
    __syncthreads();
#pragma unroll
    for (int i = 0; i < 4; ++i) {
        int y = y0 + i * 8;
        T[(size_t)(bx * 32 + y) * 768 + by * 32 + x] = f2bf(tile[x][y]);
    }
}

// ---- mask (int 0/1): masked -> valid01 = 0 (float for V-zeroing, bf16 frag)
__global__ void maskprep(const int* __restrict__ m, float* __restrict__ vz,
                         u16* __restrict__ m01, int n) {
    int i = blockIdx.x * 256 + threadIdx.x;
    if (i < n) {
        float v = m[i] ? 0.0f : 1.0f;
        vz[i] = v;
        m01[i] = f2bf(v);
    }
}

// ---------------- LayerNorm fp32 -> bf16 (optionally skipped if iter==0) ----
__global__ __launch_bounds__(256)
void ln_bf16(const float* __restrict__ in, const float* __restrict__ g,
             const float* __restrict__ bta, u16* __restrict__ out,
             const int* __restrict__ iterp, int checkIter) {
    int row = blockIdx.x, tid = threadIdx.x;
    const float* x = in + (size_t)row * D_MODEL;
    float v0 = x[tid], v1 = x[tid + 256], v2 = x[tid + 512];
    float s = v0 + v1 + v2;
    float s2 = v0 * v0 + v1 * v1 + v2 * v2;
#pragma unroll
    for (int o = 1; o < 64; o <<= 1) { s += __shfl_xor(s, o); s2 += __shfl_xor(s2, o); }
    __shared__ float sh[8];
    int w = tid >> 6;
    if ((tid & 63) == 0) { sh[w] = s; sh[4 + w] = s2; }
    __syncthreads();
    s = sh[0] + sh[1] + sh[2] + sh[3];
    s2 = sh[4] + sh[5] + sh[6] + sh[7];
    float mu = s * (1.0f / 768.0f);
    float var = s2 * (1.0f / 768.0f) - mu * mu;
    float rstd = rsqrtf(var + 1e-6f);
    bool skip = checkIter && (iterp[0] == 0);
    u16* o0 = out + (size_t)row * D_MODEL;
    if (skip) {
        o0[tid] = f2bf(v0); o0[tid + 256] = f2bf(v1); o0[tid + 512] = f2bf(v2);
    } else {
        o0[tid]       = f2bf((v0 - mu) * rstd * g[tid]       + bta[tid]);
        o0[tid + 256] = f2bf((v1 - mu) * rstd * g[tid + 256] + bta[tid + 256]);
        o0[tid + 512] = f2bf((v2 - mu) * rstd * g[tid + 512] + bta[tid + 512]);
    }
}

// ------- fused split-K reduce + residual + LN2:  v = pf0+pf1+bias+res;
//         outm = v (fp32 residual); out = bf16(LN(v))
__global__ __launch_bounds__(256)
void ln_fuse(const float* __restrict__ pf, const float* __restrict__ bias,
             const float* __restrict__ res, const float* __restrict__ g,
             const float* __restrict__ bta, float* __restrict__ outm,
             u16* __restrict__ out) {
    int row = blockIdx.x, tid = threadIdx.x;
    size_t i0 = (size_t)row * D_MODEL + tid;
    const float* pf1 = pf + (size_t)MTOT * D_MODEL;
    float v0 = pf[i0]       + pf1[i0]       + bias[tid]       + res[i0];
    float v1 = pf[i0 + 256] + pf1[i0 + 256] + bias[tid + 256] + res[i0 + 256];
    float v2 = pf[i0 + 512] + pf1[i0 + 512] + bias[tid + 512] + res[i0 + 512];
    outm[i0] = v0; outm[i0 + 256] = v1; outm[i0 + 512] = v2;
    float s = v0 + v1 + v2;
    float s2 = v0 * v0 + v1 * v1 + v2 * v2;
#pragma unroll
    for (int o = 1; o < 64; o <<= 1) { s += __shfl_xor(s, o); s2 += __shfl_xor(s2, o); }
    __shared__ float sh[8];
    int w = tid >> 6;
    if ((tid & 63) == 0) { sh[w] = s; sh[4 + w] = s2; }
    __syncthreads();
    s = sh[0] + sh[1] + sh[2] + sh[3];
    s2 = sh[4] + sh[5] + sh[6] + sh[7];
    float mu = s * (1.0f / 768.0f);
    float var = s2 * (1.0f / 768.0f) - mu * mu;
    float rstd = rsqrtf(var + 1e-6f);
    u16* o0 = out + (size_t)row * D_MODEL;
    o0[tid]       = f2bf((v0 - mu) * rstd * g[tid]       + bta[tid]);
    o0[tid + 256] = f2bf((v1 - mu) * rstd * g[tid + 256] + bta[tid + 256]);
    o0[tid + 512] = f2bf((v2 - mu) * rstd * g[tid + 512] + bta[tid + 512]);
}

// ---------------- GEMM  C = A[M][K] * Bt[N][K]^T  (bf16 in, fp32 acc) -------
// 128x128 tile, BK=32, ring-3 LDS (R11 main loop, best measured).
// MODE 0: QKV epilogue scatter (fallback path, no split-K)
// MODE 1: outF = acc + bias + res (fp32)  [raw fp32 partials if gridDim.z>1]
// MODE 2: outB = bf16(gelu(acc + bias))
// MODE 3: raw bf16 partial: oq[(z*MTOT+row)*N+col] = bf16(acc)  (QKV split-K)
template <int MODE>
__global__ __launch_bounds__(256, 3)
void gemm_bt(const u16* __restrict__ A, const u16* __restrict__ Bt,
             int K, int N,
             const float* __restrict__ bias0, const float* __restrict__ bias1,
             const float* __restrict__ bias2,
             const float* __restrict__ res,
             float* __restrict__ outF, u16* __restrict__ oq,
             u16* __restrict__ ok, u16* __restrict__ ov) {
    __shared__ __align__(16) u16 aT[3][128 * 32];
    __shared__ __align__(16) u16 bT[3][128 * 32];
    const int tid = threadIdx.x;
    const int lane = tid & 63;
    const int w = tid >> 6;
    const int wr = w >> 1, wc = w & 1;
    const int lm = lane & 15, lq = lane >> 4;
    const int bm = blockIdx.y, bn = blockIdx.x;
    const int kzlen = K / gridDim.z;
    const int kbeg = blockIdx.z * kzlen;
    const int nsteps = kzlen >> 5;

    const u16* Abase = A  + (size_t)(bm * 128) * K + kbeg;
    const u16* Bbase = Bt + (size_t)(bn * 128) * K + kbeg;

    auto stage = [&](int buf, int t) {
        int k0 = t * 32;
#pragma unroll
        for (int j = 0; j < 2; ++j) {
            int d = j * 256 + tid;          // 16B-chunk index within tile
            int row = d >> 2, p = d & 3;
            int src = (p ^ (row & 3)) * 8;
            gload16(Abase + (size_t)row * K + k0 + src, aT[buf] + (j * 256 + w * 64) * 8);
            gload16(Bbase + (size_t)row * K + k0 + src, bT[buf] + (j * 256 + w * 64) * 8);
        }
    };

    f32x4 acc[4][4] = {};
    stage(0, 0);
    if (nsteps > 1) stage(1, 1);

#pragma unroll 1
    for (int t = 0; t < nsteps; ++t) {
        if (t + 1 < nsteps) asm volatile("s_waitcnt vmcnt(4)" ::: "memory");
        else                asm volatile("s_waitcnt vmcnt(0)" ::: "memory");
        __syncthreads();
        const u16* Ab = aT[t % 3];
        const u16* Bb = bT[t % 3];
        short8 av[4], bv[4];
#pragma unroll
        for (int m = 0; m < 4; ++m) {
            int row = wr * 64 + m * 16 + lm;
            av[m] = *(const short8*)(Ab + row * 32 + ((lq ^ (row & 3)) * 8));
        }
#pragma unroll
        for (int n = 0; n < 4; ++n) {
            int row = wc * 64 + n * 16 + lm;
            bv[n] = *(const short8*)(Bb + row * 32 + ((lq ^ (row & 3)) * 8));
        }
#pragma unroll
        for (int m = 0; m < 4; ++m)
#pragma unroll
            for (int n = 0; n < 4; ++n)
                acc[m][n] = MFMA16(av[m], bv[n], acc[m][n]);
        if (t + 2 < nsteps) stage((t + 2) % 3, t + 2);   // refill ring
    }

#pragma unroll
    for (int m = 0; m < 4; ++m) {
#pragma unroll
        for (int n = 0; n < 4; ++n) {
            int col = bn * 128 + wc * 64 + n * 16 + lm;
#pragma unroll
            for (int r = 0; r < 4; ++r) {
                int row = bm * 128 + wr * 64 + m * 16 + lq * 4 + r;
                float v = acc[m][n][r];
                if (MODE == 0) {
                    int proj = col / D_MODEL;
                    int d = col - proj * D_MODEL;
                    int hh = d >> 6, dhi = d & 63;
                    int bb = row >> 11, sIdx = row & 2047;
                    if (proj == 0) {
                        v = (v + bias0[d]) * 0.18033688011112042f;
                        oq[((size_t)(bb * HEADS + hh) * SS + sIdx) * DHEAD + dhi] = f2bf(v);
                    } else if (proj == 1) {
                        v = v + bias1[d];
                        ok[((size_t)(bb * HEADS + hh) * SS + sIdx) * DHEAD + dhi] = f2bf(v);
                    } else {
                        v = (v + bias2[d]) * res[row];
                        ov[((size_t)(bb * HEADS + hh) * DHEAD + dhi) * SS + sIdx] = f2bf(v);
                    }
                } else if (MODE == 1) {
                    if (gridDim.z > 1) {
                        outF[((size_t)blockIdx.z * MTOT + row) * N + col] = v;
                    } else {
                        size_t idx = (size_t)row * N + col;
                        outF[idx] = v + bias0[col] + res[idx];
                    }
                } else if (MODE == 2) {
                    float t2 = v + bias0[col];
                    oq[(size_t)row * N + col] = f2bf(gelu_tanh_f(t2));
                } else {   // MODE 3: raw bf16 partial
                    oq[((size_t)blockIdx.z * MTOT + row) * N + col] = f2bf(v);
                }
            }
        }
    }
}

// ---------------- QKV split-K reduce + epilogue scatter ---------------------
// P = bf16 partials [2][MTOT][2304]. Zones (blockIdx.y): 0=q, 1=k, 2=v^T.
__global__ __launch_bounds__(256)
void reduce_qkv(const u16* __restrict__ P,
                const float* __restrict__ bq, const float* __restrict__ bk,
                const float* __restrict__ bv, const float* __restrict__ vz,
                u16* __restrict__ qq, u16* __restrict__ kk,
                u16* __restrict__ vt) {
    const int zone = blockIdx.y;
    const int tid = threadIdx.x;
    const u16* P1 = P + (size_t)MTOT * 2304;

    if (zone < 2) {
        // thread handles 8 consecutive cols of one row; 16B loads/stores
        int idx = blockIdx.x * 256 + tid;            // < 4096*96
        int row = idx / 96;
        int c8  = idx - row * 96;
        int col = zone * 768 + c8 * 8;
        short8 a = *(const short8*)(P  + (size_t)row * 2304 + col);
        short8 b = *(const short8*)(P1 + (size_t)row * 2304 + col);
        const float* bias = zone ? bk : bq;
        union { u16 u[8]; short8 s; } o;
#pragma unroll
        for (int e = 0; e < 8; ++e) {
            float v = bf2f((u16)a[e]) + bf2f((u16)b[e]) + bias[c8 * 8 + e];
            if (zone == 0) v *= 0.18033688011112042f;   // 1/8 * log2(e)
            o.u[e] = f2bf(v);
        }
        int d = c8 * 8, hh = d >> 6, dhi = d & 63;
        int bb = row >> 11, s = row & 2047;
        u16* dst = (zone ? kk : qq) +
                   ((size_t)(bb * HEADS + hh) * SS + s) * DHEAD + dhi;
        *(short8*)dst = o.s;
    } else {
        // v^T via LDS transpose: 64x64 tile of (row, vcol) space
        if (blockIdx.x >= 768) return;               // 64 row-tiles x 12 heads
        __shared__ u16 tile[64][72];
        int tr = blockIdx.x / 12, tc = blockIdx.x - tr * 12;
        int r0 = tr * 64;
#pragma unroll
        for (int p = 0; p < 2; ++p) {
            int lr = p * 32 + (tid >> 3);            // 0..63 local row
            int coff = (tid & 7) * 8;
            int row = r0 + lr;
            const u16* p0 = P + (size_t)row * 2304 + 1536 + tc * 64 + coff;
            short8 a = *(const short8*)p0;
            short8 b = *(const short8*)(p0 + (size_t)MTOT * 2304);
            float zf = vz[row];
#pragma unroll
            for (int e = 0; e < 8; ++e) {
                float v = (bf2f((u16)a[e]) + bf2f((u16)b[e]) +
                           bv[tc * 64 + coff + e]) * zf;
                tile[lr][coff + e] = f2bf(v);
            }
        }
        __syncthreads();
        int c = tid >> 2, sg = tid & 3;              // c: dhi, sg: 16-row group
        union { u16 u[16]; f32x4 v4[4]; } buf;
#pragma unroll
        for (int i = 0; i < 16; ++i) buf.u[i] = tile[sg * 16 + i][c];
        int bb = r0 >> 11;
        int s0 = (r0 & 2047) + sg * 16;
        u16* dst = vt + ((size_t)(bb * HEADS + tc) * DHEAD + c) * SS + s0;
        *(f32x4*)dst = buf.v4[0];
        *(f32x4*)(dst + 8) = buf.v4[1];
    }
}

// ---------------- split-K=2 reduce: out = pf[0] + pf[1] + bias + res --------
__global__ __launch_bounds__(256)
void reduce_ks2(const float* __restrict__ pf, const float* __restrict__ bias,
                const float* __restrict__ res, float* __restrict__ out, int N) {
    size_t i = ((size_t)blockIdx.x * 256 + threadIdx.x) * 4;
    f32x4 s0 = *(const f32x4*)(pf + i);
    f32x4 s1 = *(const f32x4*)(pf + (size_t)MTOT * N + i);
    int col = (int)(i % (size_t)N);
    f32x4 b = *(const f32x4*)(bias + col);
    f32x4 r = *(const f32x4*)(res + i);
    f32x4 o;
#pragma unroll
    for (int e = 0; e < 4; ++e) o[e] = s0[e] + s1[e] + b[e] + r[e];
    *(f32x4*)(out + i) = o;
}

// ---------------- flash attention: 4-wave + ring-3 (R11 version) -----------
// Max-free softmax; V rows pre-zeroed for masked keys; l = MFMA(mask01, P).
template <int NCH>
__global__ __launch_bounds__(256, 3)
void attn_fwd6(const u16* __restrict__ q, const u16* __restrict__ k,
               const u16* __restrict__ vtg, const u16* __restrict__ m01g,
               u16* __restrict__ po, float* __restrict__ pml) {
    constexpr int KLEN = SS / NCH;      // keys per chunk
    constexpr int KT   = KLEN / 64;     // 64-key tiles per chunk
    __shared__ __align__(16) u16 kls[3][64 * 64];   // [key][d], XOR-swizzled
    __shared__ __align__(16) u16 vls[3][64 * 64];   // [d][key], XOR-swizzled
    __shared__ __align__(16) u16 m01l[KLEN];        // valid01 bf16 chunk

    const int tid = threadIdx.x, lane = tid & 63, w = tid >> 6;
    const int lm = lane & 31, hi = lane >> 5;
    const int head = blockIdx.y;
    const int qblk = blockIdx.x / NCH, chunk = blockIdx.x % NCH;
    const int q0 = qblk * 128;
    const int k0 = chunk * KLEN;

    const u16* qbase = q + (size_t)head * SS * DHEAD;
    const u16* kbase = k + (size_t)head * SS * DHEAD;
    const u16* vbase = vtg + (size_t)head * DHEAD * SS;
    const u16* m01row = m01g + (head / HEADS) * SS;

    short8 qf[4];
    const int qrow = q0 + w * 32 + lm;
#pragma unroll
    for (int c = 0; c < 4; ++c)
        qf[c] = *(const short8*)(qbase + (size_t)qrow * DHEAD + c * 16 + hi * 8);

    if (tid < KLEN / 8)
        gload16(m01row + k0 + (size_t)tid * 8, m01l + (size_t)(tid >> 6) * 64 * 8);

    auto stage = [&](int buf, int t) {
#pragma unroll
        for (int j = 0; j < 2; ++j) {
            int c = j * 256 + tid;
            int row = c >> 3, jj = c & 7;
            gload16(kbase + (size_t)(k0 + t * 64 + row) * DHEAD + ((jj ^ (row & 7)) * 8),
                    kls[buf] + (j * 256 + w * 64) * 8);
            gload16(vbase + (size_t)row * SS + k0 + t * 64 + ((jj ^ (row & 7)) * 8),
                    vls[buf] + (j * 256 + w * 64) * 8);
        }
    };
    stage(0, 0);
    if (KT > 1) stage(1, 1);

    f32x16 o0 = {}, o1 = {}, accl = {};

#pragma unroll 1
    for (int t = 0; t < KT; ++t) {
        if (t + 1 < KT) asm volatile("s_waitcnt vmcnt(4)" ::: "memory");
        else            asm volatile("s_waitcnt vmcnt(0)" ::: "memory");
        __syncthreads();
        const u16* kb = kls[t % 3];
        const u16* vb = vls[t % 3];
#pragma unroll
        for (int s = 0; s < 2; ++s) {
            short8 av[4];
#pragma unroll
            for (int c = 0; c < 4; ++c)
                av[c] = *(const short8*)(kb + (s * 32 + lm) * 64 + (((c * 2 + hi) ^ (lm & 7)) * 8));
            short8 vf[4];
#pragma unroll
            for (int kc = 0; kc < 2; ++kc)
#pragma unroll
                for (int df = 0; df < 2; ++df)
                    vf[kc * 2 + df] = *(const short8*)(vb + (df * 32 + lm) * 64 +
                                                       (((s * 4 + kc * 2 + hi) ^ (lm & 7)) * 8));
            short8 mf0 = *(const short8*)(m01l + t * 64 + s * 32 + hi * 8);
            short8 mf1 = *(const short8*)(m01l + t * 64 + s * 32 + 16 + hi * 8);

            f32x16 st = {};
#pragma unroll
            for (int c = 0; c < 4; ++c) st = MFMA32(av[c], qf[c], st);

            float p[16];
#pragma unroll
            for (int r = 0; r < 16; ++r) p[r] = exp2_fast(st[r]);

            u32 W[8];
#pragma unroll
            for (int t8 = 0; t8 < 8; ++t8) W[t8] = cvtpk(p[2 * t8], p[2 * t8 + 1]);
            union { u32 wd[4]; short8 s8; } pf0, pf1;
            u32 a0w = W[0], b0w = W[2]; plswap(a0w, b0w, hi);
            u32 a1w = W[1], b1w = W[3]; plswap(a1w, b1w, hi);
            u32 a2w = W[4], b2w = W[6]; plswap(a2w, b2w, hi);
            u32 a3w = W[5], b3w = W[7]; plswap(a3w, b3w, hi);
            pf0.wd[0] = a0w; pf0.wd[1] = a1w; pf0.wd[2] = b0w; pf0.wd[3] = b1w;
            pf1.wd[0] = a2w; pf1.wd[1] = a3w; pf1.wd[2] = b2w; pf1.wd[3] = b3w;

            accl = MFMA32(mf0, pf0.s8, accl);
            accl = MFMA32(mf1, pf1.s8, accl);
            o0 = MFMA32(vf[0], pf0.s8, o0);
            o1 = MFMA32(vf[1], pf0.s8, o1);
            o0 = MFMA32(vf[2], pf1.s8, o0);
            o1 = MFMA32(vf[3], pf1.s8, o1);
        }
        if (t + 2 < KT) stage((t + 2) % 3, t + 2);
    }

    const int pc = (head * 16 + qblk) * NCH + chunk;
    u16* orow = po + ((size_t)pc * 128 + (w * 32 + lm)) * 64;
#pragma unroll
    for (int g = 0; g < 4; ++g) {
        short4v pk0, pk1;
#pragma unroll
        for (int e = 0; e < 4; ++e) {
            pk0[e] = (short)f2bf(o0[g * 4 + e]);
            pk1[e] = (short)f2bf(o1[g * 4 + e]);
        }
        *(short4v*)(orow + g * 8 + hi * 4) = pk0;
        *(short4v*)(orow + 32 + g * 8 + hi * 4) = pk1;
    }
    if (hi == 0)
        pml[(size_t)pc * 128 + (w * 32 + lm)] = accl[0];
}

// ---------------- merge split-K partials -> ctx bf16 [B,S,H*64] ------------
__global__ __launch_bounds__(256)
void attn_merge(const u16* __restrict__ po, const float* __restrict__ pml,
                u16* __restrict__ ctx, int nch) {
    const int head = blockIdx.y;
    const int bb = head / HEADS, hh = head % HEADS;
    const int rl = threadIdx.x >> 4, dg = threadIdx.x & 15;
    const int s = blockIdx.x * 16 + rl;
    const int qb = s >> 7, qr = s & 127;
    const int pcb = (head * 16 + qb) * nch;

    float denom = 0.0f;
    float acc[4] = {0.0f, 0.0f, 0.0f, 0.0f};
#pragma unroll 4
    for (int c = 0; c < nch; ++c) {
        denom += pml[((size_t)(pcb + c)) * 128 + qr];
        const u16* op = po + (((size_t)(pcb + c) * 128 + qr) * 64) + dg * 4;
        short4v a = *(const short4v*)op;
#pragma unroll
        for (int e = 0; e < 4; ++e) acc[e] += bf2f((u16)a[e]);
    }
    float inv = 1.0f / denom;
    short4v r;
#pragma unroll
    for (int e = 0; e < 4; ++e) r[e] = (short)f2bf(acc[e] * inv);
    *(short4v*)(ctx + ((size_t)(bb * SS + s)) * D_MODEL + hh * DHEAD + dg * 4) = r;
}

// ---------------------------------------------------------------------------
extern "C" void kernel_launch(void* const* d_in, const int* in_sizes, int n_in,
                              void* d_out, int out_size, void* d_ws, size_t ws_size,
                              hipStream_t stream) {
    const int*   iterp  = (const int*)  d_in[0];
    const float* inputs = (const float*)d_in[2];
    const int*   mask   = (const int*)  d_in[3];
    const float* Wq = (const float*)d_in[4];
    const float* bq = (const float*)d_in[5];
    const float* Wk = (const float*)d_in[6];
    const float* bk = (const float*)d_in[7];
    const float* Wv = (const float*)d_in[8];
    const float* bv = (const float*)d_in[9];
    const float* Wo = (const float*)d_in[10];
    const float* bo = (const float*)d_in[11];
    const float* ln1g = (const float*)d_in[12];
    const float* ln1b = (const float*)d_in[13];
    const float* W1 = (const float*)d_in[14];
    const float* b1 = (const float*)d_in[15];
    const float* W2 = (const float*)d_in[16];
    const float* b2 = (const float*)d_in[17];
    const float* ln2g = (const float*)d_in[18];
    const float* ln2b = (const float*)d_in[19];
    float* outp = (float*)d_out;

    char* ws = (char*)d_ws;
    size_t off = 0;
    auto alloc = [&](size_t bytes) -> void* {
        void* p = ws + off;
        off += (bytes + 255) & ~(size_t)255;
        return p;
    };
    u16*   wqkv_t = (u16*)  alloc((size_t)2304 * 768 * 2);
    u16*   wo_t   = (u16*)  alloc((size_t)768 * 768 * 2);
    u16*   w1_t   = (u16*)  alloc((size_t)3072 * 768 * 2);
    u16*   w2_t   = (u16*)  alloc((size_t)768 * 3072 * 2);
    float* vzf    = (float*)alloc((size_t)MTOT * 4);        // valid01 fp32
    u16*   m01    = (u16*)  alloc((size_t)MTOT * 2);        // valid01 bf16
    u16*   xh     = (u16*)  alloc((size_t)MTOT * 768 * 2);  // x / h / attn l
    u16*   qb     = (u16*)  alloc((size_t)MTOT * 768 * 2);
    u16*   kbuf   = (u16*)  alloc((size_t)MTOT * 768 * 2);
    u16*   vtb    = (u16*)  alloc((size_t)MTOT * 768 * 2);
    u16*   ctxb   = (u16*)  alloc((size_t)MTOT * 768 * 2);
    float* outm   = (float*)alloc((size_t)MTOT * 768 * 4);  // 12.58 MB
    u16*   inter  = qb;  // reuse q|k|vt|ctx region

    // fp32 split-K partial buffer for the skinny GEMMs (Wo, FFN2): 25.2 MB.
    // NOTE: allocated immediately after outm -> outm..pfbuf is one contiguous
    // 37.8 MB span (sizes are 256-multiple), used as the QKV bf16 partial P.
    float* pfbuf = (float*)alloc((size_t)2 * MTOT * 768 * 4);
    const bool split_ok = (off <= ws_size);   // fallback if ws too small

    float* pml = (float*)xh;

    dim3 blk(256);
    transpose_cast4<<<dim3(24, 24, 4), blk, 0, stream>>>(
        Wq, Wk, Wv, Wo,
        wqkv_t, wqkv_t + 768 * 768, wqkv_t + 2 * 768 * 768, wo_t);
    transpose_cast<<<dim3(96, 24), blk, 0, stream>>>(W1, w1_t, 768, 3072);
    transpose_cast<<<dim3(24, 96), blk, 0, stream>>>(W2, w2_t, 3072, 768);
    maskprep<<<dim3(16), blk, 0, stream>>>(mask, vzf, m01, MTOT);

    // x = LN1(inputs) (skipped if iter==0), bf16
    ln_bf16<<<dim3(MTOT), blk, 0, stream>>>(inputs, ln1g, ln1b, xh, iterp, 1);

    // fused QKV projection — split-K=2 (grid 1152 = 4.5 blocks/CU candidates)
    // bf16 partials P alias outm+pfbuf (37.8 MB); reduce does bias/scale/
    // mask-zero + coalesced scatter (incl. v^T via LDS transpose).
    if (split_ok) {
        u16* P = (u16*)outm;
        gemm_bt<3><<<dim3(2304 / 128, MTOT / 128, 2), blk, 0, stream>>>(
            xh, wqkv_t, 768, 2304, nullptr, nullptr, nullptr, nullptr,
            nullptr, P, nullptr, nullptr);
        reduce_qkv<<<dim3(1536, 3), blk, 0, stream>>>(
            P, bq, bk, bv, vzf, qb, kbuf, vtb);
    } else {
        gemm_bt<0><<<dim3(2304 / 128, MTOT / 128), blk, 0, stream>>>(
            xh, wqkv_t, 768, 2304, bq, bk, bv, vzf, nullptr, qb, kbuf, vtb);
    }

    // flash attention: 4-wave blocks, ring-3, split-K=4
    if (split_ok) {
        u16* po = (u16*)pfbuf;
        attn_fwd6<4><<<dim3(16 * 4, BB * HEADS), blk, 0, stream>>>(
            qb, kbuf, vtb, m01, po, pml);
        attn_merge<<<dim3(SS / 16, BB * HEADS), blk, 0, stream>>>(po, pml, ctxb, 4);
    } else {
        u16* po = (u16*)outm;
        attn_fwd6<2><<<dim3(16 * 2, BB * HEADS), blk, 0, stream>>>(
            qb, kbuf, vtb, m01, po, pml);
        attn_merge<<<dim3(SS / 16, BB * HEADS), blk, 0, stream>>>(po, pml, ctxb, 2);
    }

    // out = ctx @ Wo + bo + inputs; h = LN2(out)
    if (split_ok) {
        gemm_bt<1><<<dim3(768 / 128, MTOT / 128, 2), blk, 0, stream>>>(
            ctxb, wo_t, 768, 768, nullptr, nullptr, nullptr, nullptr,
            pfbuf, nullptr, nullptr, nullptr);
        ln_fuse<<<dim3(MTOT), blk, 0, stream>>>(pfbuf, bo, inputs, ln2g, ln2b, outm, xh);
    } else {
        gemm_bt<1><<<dim3(768 / 128, MTOT / 128), blk, 0, stream>>>(
            ctxb, wo_t, 768, 768, bo, nullptr, nullptr, inputs, outm, nullptr, nullptr, nullptr);
        ln_bf16<<<dim3(MTOT), blk, 0, stream>>>(outm, ln2g, ln2b, xh, iterp, 0);
    }

    // inter = gelu(h @ W1 + b1), bf16  (768 blocks = 3/CU — CONTROL dispatch)
    gemm_bt<2><<<dim3(3072 / 128, MTOT / 128), blk, 0, stream>>>(
        xh, w1_t, 768, 3072, b1, nullptr, nullptr, nullptr, nullptr, inter, nullptr, nullptr);

    // d_out = inter @ W2 + b2 + out  (fp32)  — split-K=2 -> 384 blocks
    if (split_ok) {
        gemm_bt<1><<<dim3(768 / 128, MTOT / 128, 2), blk, 0, stream>>>(
            inter, w2_t, 3072, 768, nullptr, nullptr, nullptr, nullptr,
            pfbuf, nullptr, nullptr, nullptr);
        reduce_ks2<<<dim3(MTOT * 768 / 1024), blk, 0, stream>>>(pfbuf, b2, outm, outp, 768);
    } else {
        gemm_bt<1><<<dim3(768 / 128, MTOT / 128), blk, 0, stream>>>(
            inter, w2_t, 3072, 768, b2, nullptr, nullptr, outm, outp, nullptr, nullptr, nullptr);
    }
}

// Round 15
// 218.647 us; speedup vs baseline: 1.0011x; 1.0011x over previous
//
#include <hip/hip_runtime.h>
#include <hip/hip_bf16.h>
#include <stdint.h>

#define D_MODEL 768
#define HEADS   12
#define DHEAD   64
#define D_FF    3072
#define BB      2
#define SS      2048
#define MTOT    (BB*SS)   // 4096

typedef uint16_t u16;
typedef uint32_t u32;
typedef __attribute__((ext_vector_type(8))) short short8;
typedef __attribute__((ext_vector_type(4))) short short4v;
typedef __attribute__((ext_vector_type(4))) float f32x4;
typedef __attribute__((ext_vector_type(16))) float f32x16;
typedef __attribute__((ext_vector_type(2))) unsigned uint2v;

__device__ __forceinline__ u16 f2bf(float f) {
    union { float f; u32 u; } v; v.f = f;
    u32 r = v.u + 0x7fffu + ((v.u >> 16) & 1u);
    return (u16)(r >> 16);
}

__device__ __forceinline__ float bf2f(u16 u) {
    union { u32 u; float f; } v; v.u = ((u32)u) << 16;
    return v.f;
}

// raw v_exp_f32 (2^x): scores bounded |x|<~16, no OCML range-check expansion
__device__ __forceinline__ float exp2_fast(float x) {
#if __has_builtin(__builtin_amdgcn_exp2f)
    return __builtin_amdgcn_exp2f(x);
#else
    return exp2f(x);
#endif
}

// packed bf16 convert: dst = {bf16(a) lo, bf16(b) hi}  (T12 recipe)
__device__ __forceinline__ u32 cvtpk(float a, float b) {
    u32 r;
    asm("v_cvt_pk_bf16_f32 %0, %1, %2" : "=v"(r) : "v"(a), "v"(b));
    return r;
}

// half-wave exchange: a' = [a.row0, b.row0], b' = [a.row1, b.row1]
__device__ __forceinline__ void plswap(u32& a, u32& b, int hi) {
#if __has_builtin(__builtin_amdgcn_permlane32_swap)
    uint2v r = __builtin_amdgcn_permlane32_swap(a, b, false, false);
    a = r[0]; b = r[1];
#else
    u32 ax = (u32)__shfl_xor((int)a, 32), bx = (u32)__shfl_xor((int)b, 32);
    u32 na = hi ? bx : a, nb = hi ? b : ax;
    a = na; b = nb;
#endif
}

__device__ __forceinline__ void gload16(const void* g, void* l) {
    __builtin_amdgcn_global_load_lds(
        (const __attribute__((address_space(1))) u32*)g,
        (__attribute__((address_space(3))) u32*)l, 16, 0, 0);
}

#define MFMA16(a, b, c) __builtin_amdgcn_mfma_f32_16x16x32_bf16((a), (b), (c), 0, 0, 0)
#define MFMA32(a, b, c) __builtin_amdgcn_mfma_f32_32x32x16_bf16((a), (b), (c), 0, 0, 0)

__device__ __forceinline__ float gelu_tanh_f(float x) {
    float x3 = x * x * x;
    return 0.5f * x * (1.0f + tanhf(0.7978845608028654f * (x + 0.044715f * x3)));
}

// ---------------- weight transpose + cast: W[R][C] fp32 -> Wt[C][R] bf16 ----
__global__ __launch_bounds__(256)
void transpose_cast(const float* __restrict__ W, u16* __restrict__ Wt, int R, int C) {
    __shared__ float tile[32][33];
    int bx = blockIdx.x, by = blockIdx.y;
    int x = threadIdx.x & 31, y0 = threadIdx.x >> 5;
#pragma unroll
    for (int i = 0; i < 4; ++i) {
        int y = y0 + i * 8;
        tile[y][x] = W[(size_t)(by * 32 + y) * C + bx * 32 + x];
    }
    __syncthreads();
#pragma unroll
    for (int i = 0; i < 4; ++i) {
        int y = y0 + i * 8;
        Wt[(size_t)(bx * 32 + y) * R + by * 32 + x] = f2bf(tile[x][y]);
    }
}

// batched 768x768 transpose: z selects among 4 weight matrices
__global__ __launch_bounds__(256)
void transpose_cast4(const float* __restrict__ W0, const float* __restrict__ W1,
                     const float* __restrict__ W2, const float* __restrict__ W3,
                     u16* __restrict__ T0, u16* __restrict__ T1,
                     u16* __restrict__ T2, u16* __restrict__ T3) {
    const int z = blockIdx.z;
    const float* W = z == 0 ? W0 : z == 1 ? W1 : z == 2 ? W2 : W3;
    u16*         T = z == 0 ? T0 : z == 1 ? T1 : z == 2 ? T2 : T3;
    __shared__ float tile[32][33];
    int bx = blockIdx.x, by = blockIdx.y;
    int x = threadIdx.x & 31, y0 = threadIdx.x >> 5;
#pragma unroll
    for (int i = 0; i < 4; ++i) {
        int y = y0 + i * 8;
        tile[y][x] = W[(size_t)(by * 32 + y) * 768 + bx * 32 + x];
    }
    __syncthreads();
#pragma unroll
    for (int i = 0; i < 4; ++i) {
        int y = y0 + i * 8;
        T[(size_t)(bx * 32 + y) * 768 + by * 32 + x] = f2bf(tile[x][y]);
    }
}

// ---- mask (int 0/1): masked -> valid01 = 0 (float for V-zeroing, bf16 frag)
__global__ void maskprep(const int* __restrict__ m, float* __restrict__ vz,
                         u16* __restrict__ m01, int n) {
    int i = blockIdx.x * 256 + threadIdx.x;
    if (i < n) {
        float v = m[i] ? 0.0f : 1.0f;
        vz[i] = v;
        m01[i] = f2bf(v);
    }
}

// ---------------- LayerNorm fp32 -> bf16 (optionally skipped if iter==0) ----
__global__ __launch_bounds__(256)
void ln_bf16(const float* __restrict__ in, const float* __restrict__ g,
             const float* __restrict__ bta, u16* __restrict__ out,
             const int* __restrict__ iterp, int checkIter) {
    int row = blockIdx.x, tid = threadIdx.x;
    const float* x = in + (size_t)row * D_MODEL;
    float v0 = x[tid], v1 = x[tid + 256], v2 = x[tid + 512];
    float s = v0 + v1 + v2;
    float s2 = v0 * v0 + v1 * v1 + v2 * v2;
#pragma unroll
    for (int o = 1; o < 64; o <<= 1) { s += __shfl_xor(s, o); s2 += __shfl_xor(s2, o); }
    __shared__ float sh[8];
    int w = tid >> 6;
    if ((tid & 63) == 0) { sh[w] = s; sh[4 + w] = s2; }
    __syncthreads();
    s = sh[0] + sh[1] + sh[2] + sh[3];
    s2 = sh[4] + sh[5] + sh[6] + sh[7];
    float mu = s * (1.0f / 768.0f);
    float var = s2 * (1.0f / 768.0f) - mu * mu;
    float rstd = rsqrtf(var + 1e-6f);
    bool skip = checkIter && (iterp[0] == 0);
    u16* o0 = out + (size_t)row * D_MODEL;
    if (skip) {
        o0[tid] = f2bf(v0); o0[tid + 256] = f2bf(v1); o0[tid + 512] = f2bf(v2);
    } else {
        o0[tid]       = f2bf((v0 - mu) * rstd * g[tid]       + bta[tid]);
        o0[tid + 256] = f2bf((v1 - mu) * rstd * g[tid + 256] + bta[tid + 256]);
        o0[tid + 512] = f2bf((v2 - mu) * rstd * g[tid + 512] + bta[tid + 512]);
    }
}

// ------- fused split-K reduce + residual + LN2:  v = pf0+pf1+bias+res;
//         outm = v (fp32 residual); out = bf16(LN(v))
__global__ __launch_bounds__(256)
void ln_fuse(const float* __restrict__ pf, const float* __restrict__ bias,
             const float* __restrict__ res, const float* __restrict__ g,
             const float* __restrict__ bta, float* __restrict__ outm,
             u16* __restrict__ out) {
    int row = blockIdx.x, tid = threadIdx.x;
    size_t i0 = (size_t)row * D_MODEL + tid;
    const float* pf1 = pf + (size_t)MTOT * D_MODEL;
    float v0 = pf[i0]       + pf1[i0]       + bias[tid]       + res[i0];
    float v1 = pf[i0 + 256] + pf1[i0 + 256] + bias[tid + 256] + res[i0 + 256];
    float v2 = pf[i0 + 512] + pf1[i0 + 512] + bias[tid + 512] + res[i0 + 512];
    outm[i0] = v0; outm[i0 + 256] = v1; outm[i0 + 512] = v2;
    float s = v0 + v1 + v2;
    float s2 = v0 * v0 + v1 * v1 + v2 * v2;
#pragma unroll
    for (int o = 1; o < 64; o <<= 1) { s += __shfl_xor(s, o); s2 += __shfl_xor(s2, o); }
    __shared__ float sh[8];
    int w = tid >> 6;
    if ((tid & 63) == 0) { sh[w] = s; sh[4 + w] = s2; }
    __syncthreads();
    s = sh[0] + sh[1] + sh[2] + sh[3];
    s2 = sh[4] + sh[5] + sh[6] + sh[7];
    float mu = s * (1.0f / 768.0f);
    float var = s2 * (1.0f / 768.0f) - mu * mu;
    float rstd = rsqrtf(var + 1e-6f);
    u16* o0 = out + (size_t)row * D_MODEL;
    o0[tid]       = f2bf((v0 - mu) * rstd * g[tid]       + bta[tid]);
    o0[tid + 256] = f2bf((v1 - mu) * rstd * g[tid + 256] + bta[tid + 256]);
    o0[tid + 512] = f2bf((v2 - mu) * rstd * g[tid + 512] + bta[tid + 512]);
}

// ---------------- GEMM  C = A[M][K] * Bt[N][K]^T  (bf16 in, fp32 acc) -------
// 128x128 tile, BK=32, ring-3 LDS (R11 main loop, best measured).
// MODE 0: QKV epilogue scatter (fallback path, no split-K)
// MODE 1: outF = acc + bias + res (fp32)  [raw fp32 partials if gridDim.z>1]
// MODE 2: outB = bf16(gelu(acc + bias))
// MODE 3: raw bf16 partial: oq[(z*MTOT+row)*N+col] = bf16(acc)  (QKV split-K)
template <int MODE>
__global__ __launch_bounds__(256, 3)
void gemm_bt(const u16* __restrict__ A, const u16* __restrict__ Bt,
             int K, int N,
             const float* __restrict__ bias0, const float* __restrict__ bias1,
             const float* __restrict__ bias2,
             const float* __restrict__ res,
             float* __restrict__ outF, u16* __restrict__ oq,
             u16* __restrict__ ok, u16* __restrict__ ov) {
    __shared__ __align__(16) u16 aT[3][128 * 32];
    __shared__ __align__(16) u16 bT[3][128 * 32];
    const int tid = threadIdx.x;
    const int lane = tid & 63;
    const int w = tid >> 6;
    const int wr = w >> 1, wc = w & 1;
    const int lm = lane & 15, lq = lane >> 4;
    const int bm = blockIdx.y, bn = blockIdx.x;
    const int kzlen = K / gridDim.z;
    const int kbeg = blockIdx.z * kzlen;
    const int nsteps = kzlen >> 5;

    const u16* Abase = A  + (size_t)(bm * 128) * K + kbeg;
    const u16* Bbase = Bt + (size_t)(bn * 128) * K + kbeg;

    auto stage = [&](int buf, int t) {
        int k0 = t * 32;
#pragma unroll
        for (int j = 0; j < 2; ++j) {
            int d = j * 256 + tid;          // 16B-chunk index within tile
            int row = d >> 2, p = d & 3;
            int src = (p ^ (row & 3)) * 8;
            gload16(Abase + (size_t)row * K + k0 + src, aT[buf] + (j * 256 + w * 64) * 8);
            gload16(Bbase + (size_t)row * K + k0 + src, bT[buf] + (j * 256 + w * 64) * 8);
        }
    };

    f32x4 acc[4][4] = {};
    stage(0, 0);
    if (nsteps > 1) stage(1, 1);

#pragma unroll 1
    for (int t = 0; t < nsteps; ++t) {
        if (t + 1 < nsteps) asm volatile("s_waitcnt vmcnt(4)" ::: "memory");
        else                asm volatile("s_waitcnt vmcnt(0)" ::: "memory");
        __syncthreads();
        const u16* Ab = aT[t % 3];
        const u16* Bb = bT[t % 3];
        short8 av[4], bv[4];
#pragma unroll
        for (int m = 0; m < 4; ++m) {
            int row = wr * 64 + m * 16 + lm;
            av[m] = *(const short8*)(Ab + row * 32 + ((lq ^ (row & 3)) * 8));
        }
#pragma unroll
        for (int n = 0; n < 4; ++n) {
            int row = wc * 64 + n * 16 + lm;
            bv[n] = *(const short8*)(Bb + row * 32 + ((lq ^ (row & 3)) * 8));
        }
#pragma unroll
        for (int m = 0; m < 4; ++m)
#pragma unroll
            for (int n = 0; n < 4; ++n)
                acc[m][n] = MFMA16(av[m], bv[n], acc[m][n]);
        if (t + 2 < nsteps) stage((t + 2) % 3, t + 2);   // refill ring
    }

#pragma unroll
    for (int m = 0; m < 4; ++m) {
#pragma unroll
        for (int n = 0; n < 4; ++n) {
            int col = bn * 128 + wc * 64 + n * 16 + lm;
#pragma unroll
            for (int r = 0; r < 4; ++r) {
                int row = bm * 128 + wr * 64 + m * 16 + lq * 4 + r;
                float v = acc[m][n][r];
                if (MODE == 0) {
                    int proj = col / D_MODEL;
                    int d = col - proj * D_MODEL;
                    int hh = d >> 6, dhi = d & 63;
                    int bb = row >> 11, sIdx = row & 2047;
                    if (proj == 0) {
                        v = (v + bias0[d]) * 0.18033688011112042f;
                        oq[((size_t)(bb * HEADS + hh) * SS + sIdx) * DHEAD + dhi] = f2bf(v);
                    } else if (proj == 1) {
                        v = v + bias1[d];
                        ok[((size_t)(bb * HEADS + hh) * SS + sIdx) * DHEAD + dhi] = f2bf(v);
                    } else {
                        v = (v + bias2[d]) * res[row];
                        ov[((size_t)(bb * HEADS + hh) * DHEAD + dhi) * SS + sIdx] = f2bf(v);
                    }
                } else if (MODE == 1) {
                    if (gridDim.z > 1) {
                        outF[((size_t)blockIdx.z * MTOT + row) * N + col] = v;
                    } else {
                        size_t idx = (size_t)row * N + col;
                        outF[idx] = v + bias0[col] + res[idx];
                    }
                } else if (MODE == 2) {
                    float t2 = v + bias0[col];
                    oq[(size_t)row * N + col] = f2bf(gelu_tanh_f(t2));
                } else {   // MODE 3: raw bf16 partial
                    oq[((size_t)blockIdx.z * MTOT + row) * N + col] = f2bf(v);
                }
            }
        }
    }
}

// ---------------- QKV split-K reduce + epilogue scatter ---------------------
// P = bf16 partials [2][MTOT][2304]. Zones (blockIdx.y): 0=q, 1=k, 2=v^T.
__global__ __launch_bounds__(256)
void reduce_qkv(const u16* __restrict__ P,
                const float* __restrict__ bq, const float* __restrict__ bk,
                const float* __restrict__ bv, const float* __restrict__ vz,
                u16* __restrict__ qq, u16* __restrict__ kk,
                u16* __restrict__ vt) {
    const int zone = blockIdx.y;
    const int tid = threadIdx.x;
    const u16* P1 = P + (size_t)MTOT * 2304;

    if (zone < 2) {
        // thread handles 8 consecutive cols of one row; 16B loads/stores
        int idx = blockIdx.x * 256 + tid;            // < 4096*96
        int row = idx / 96;
        int c8  = idx - row * 96;
        int col = zone * 768 + c8 * 8;
        short8 a = *(const short8*)(P  + (size_t)row * 2304 + col);
        short8 b = *(const short8*)(P1 + (size_t)row * 2304 + col);
        const float* bias = zone ? bk : bq;
        union { u16 u[8]; short8 s; } o;
#pragma unroll
        for (int e = 0; e < 8; ++e) {
            float v = bf2f((u16)a[e]) + bf2f((u16)b[e]) + bias[c8 * 8 + e];
            if (zone == 0) v *= 0.18033688011112042f;   // 1/8 * log2(e)
            o.u[e] = f2bf(v);
        }
        int d = c8 * 8, hh = d >> 6, dhi = d & 63;
        int bb = row >> 11, s = row & 2047;
        u16* dst = (zone ? kk : qq) +
                   ((size_t)(bb * HEADS + hh) * SS + s) * DHEAD + dhi;
        *(short8*)dst = o.s;
    } else {
        // v^T via LDS transpose: 64x64 tile of (row, vcol) space
        if (blockIdx.x >= 768) return;               // 64 row-tiles x 12 heads
        __shared__ u16 tile[64][72];
        int tr = blockIdx.x / 12, tc = blockIdx.x - tr * 12;
        int r0 = tr * 64;
#pragma unroll
        for (int p = 0; p < 2; ++p) {
            int lr = p * 32 + (tid >> 3);            // 0..63 local row
            int coff = (tid & 7) * 8;
            int row = r0 + lr;
            const u16* p0 = P + (size_t)row * 2304 + 1536 + tc * 64 + coff;
            short8 a = *(const short8*)p0;
            short8 b = *(const short8*)(p0 + (size_t)MTOT * 2304);
            float zf = vz[row];
#pragma unroll
            for (int e = 0; e < 8; ++e) {
                float v = (bf2f((u16)a[e]) + bf2f((u16)b[e]) +
                           bv[tc * 64 + coff + e]) * zf;
                tile[lr][coff + e] = f2bf(v);
            }
        }
        __syncthreads();
        int c = tid >> 2, sg = tid & 3;              // c: dhi, sg: 16-row group
        union { u16 u[16]; f32x4 v4[4]; } buf;
#pragma unroll
        for (int i = 0; i < 16; ++i) buf.u[i] = tile[sg * 16 + i][c];
        int bb = r0 >> 11;
        int s0 = (r0 & 2047) + sg * 16;
        u16* dst = vt + ((size_t)(bb * HEADS + tc) * DHEAD + c) * SS + s0;
        *(f32x4*)dst = buf.v4[0];
        *(f32x4*)(dst + 8) = buf.v4[1];
    }
}

// ---------------- split-K=2 reduce: out = pf[0] + pf[1] + bias + res --------
__global__ __launch_bounds__(256)
void reduce_ks2(const float* __restrict__ pf, const float* __restrict__ bias,
                const float* __restrict__ res, float* __restrict__ out, int N) {
    size_t i = ((size_t)blockIdx.x * 256 + threadIdx.x) * 4;
    f32x4 s0 = *(const f32x4*)(pf + i);
    f32x4 s1 = *(const f32x4*)(pf + (size_t)MTOT * N + i);
    int col = (int)(i % (size_t)N);
    f32x4 b = *(const f32x4*)(bias + col);
    f32x4 r = *(const f32x4*)(res + i);
    f32x4 o;
#pragma unroll
    for (int e = 0; e < 4; ++e) o[e] = s0[e] + s1[e] + b[e] + r[e];
    *(f32x4*)(out + i) = o;
}

// ---------------- flash attention: 4-wave + ring-3 (R11 version) -----------
// Max-free softmax; V rows pre-zeroed for masked keys; l = MFMA(mask01, P).
template <int NCH>
__global__ __launch_bounds__(256, 3)
void attn_fwd6(const u16* __restrict__ q, const u16* __restrict__ k,
               const u16* __restrict__ vtg, const u16* __restrict__ m01g,
               u16* __restrict__ po, float* __restrict__ pml) {
    constexpr int KLEN = SS / NCH;      // keys per chunk
    constexpr int KT   = KLEN / 64;     // 64-key tiles per chunk
    __shared__ __align__(16) u16 kls[3][64 * 64];   // [key][d], XOR-swizzled
    __shared__ __align__(16) u16 vls[3][64 * 64];   // [d][key], XOR-swizzled
    __shared__ __align__(16) u16 m01l[KLEN];        // valid01 bf16 chunk

    const int tid = threadIdx.x, lane = tid & 63, w = tid >> 6;
    const int lm = lane & 31, hi = lane >> 5;
    const int head = blockIdx.y;
    const int qblk = blockIdx.x / NCH, chunk = blockIdx.x % NCH;
    const int q0 = qblk * 128;
    const int k0 = chunk * KLEN;

    const u16* qbase = q + (size_t)head * SS * DHEAD;
    const u16* kbase = k + (size_t)head * SS * DHEAD;
    const u16* vbase = vtg + (size_t)head * DHEAD * SS;
    const u16* m01row = m01g + (head / HEADS) * SS;

    short8 qf[4];
    const int qrow = q0 + w * 32 + lm;
#pragma unroll
    for (int c = 0; c < 4; ++c)
        qf[c] = *(const short8*)(qbase + (size_t)qrow * DHEAD + c * 16 + hi * 8);

    if (tid < KLEN / 8)
        gload16(m01row + k0 + (size_t)tid * 8, m01l + (size_t)(tid >> 6) * 64 * 8);

    auto stage = [&](int buf, int t) {
#pragma unroll
        for (int j = 0; j < 2; ++j) {
            int c = j * 256 + tid;
            int row = c >> 3, jj = c & 7;
            gload16(kbase + (size_t)(k0 + t * 64 + row) * DHEAD + ((jj ^ (row & 7)) * 8),
                    kls[buf] + (j * 256 + w * 64) * 8);
            gload16(vbase + (size_t)row * SS + k0 + t * 64 + ((jj ^ (row & 7)) * 8),
                    vls[buf] + (j * 256 + w * 64) * 8);
        }
    };
    stage(0, 0);
    if (KT > 1) stage(1, 1);

    f32x16 o0 = {}, o1 = {}, accl = {};

#pragma unroll 1
    for (int t = 0; t < KT; ++t) {
        if (t + 1 < KT) asm volatile("s_waitcnt vmcnt(4)" ::: "memory");
        else            asm volatile("s_waitcnt vmcnt(0)" ::: "memory");
        __syncthreads();
        const u16* kb = kls[t % 3];
        const u16* vb = vls[t % 3];
#pragma unroll
        for (int s = 0; s < 2; ++s) {
            short8 av[4];
#pragma unroll
            for (int c = 0; c < 4; ++c)
                av[c] = *(const short8*)(kb + (s * 32 + lm) * 64 + (((c * 2 + hi) ^ (lm & 7)) * 8));
            short8 vf[4];
#pragma unroll
            for (int kc = 0; kc < 2; ++kc)
#pragma unroll
                for (int df = 0; df < 2; ++df)
                    vf[kc * 2 + df] = *(const short8*)(vb + (df * 32 + lm) * 64 +
                                                       (((s * 4 + kc * 2 + hi) ^ (lm & 7)) * 8));
            short8 mf0 = *(const short8*)(m01l + t * 64 + s * 32 + hi * 8);
            short8 mf1 = *(const short8*)(m01l + t * 64 + s * 32 + 16 + hi * 8);

            f32x16 st = {};
#pragma unroll
            for (int c = 0; c < 4; ++c) st = MFMA32(av[c], qf[c], st);

            float p[16];
#pragma unroll
            for (int r = 0; r < 16; ++r) p[r] = exp2_fast(st[r]);

            u32 W[8];
#pragma unroll
            for (int t8 = 0; t8 < 8; ++t8) W[t8] = cvtpk(p[2 * t8], p[2 * t8 + 1]);
            union { u32 wd[4]; short8 s8; } pf0, pf1;
            u32 a0w = W[0], b0w = W[2]; plswap(a0w, b0w, hi);
            u32 a1w = W[1], b1w = W[3]; plswap(a1w, b1w, hi);
            u32 a2w = W[4], b2w = W[6]; plswap(a2w, b2w, hi);
            u32 a3w = W[5], b3w = W[7]; plswap(a3w, b3w, hi);
            pf0.wd[0] = a0w; pf0.wd[1] = a1w; pf0.wd[2] = b0w; pf0.wd[3] = b1w;
            pf1.wd[0] = a2w; pf1.wd[1] = a3w; pf1.wd[2] = b2w; pf1.wd[3] = b3w;

            accl = MFMA32(mf0, pf0.s8, accl);
            accl = MFMA32(mf1, pf1.s8, accl);
            o0 = MFMA32(vf[0], pf0.s8, o0);
            o1 = MFMA32(vf[1], pf0.s8, o1);
            o0 = MFMA32(vf[2], pf1.s8, o0);
            o1 = MFMA32(vf[3], pf1.s8, o1);
        }
        if (t + 2 < KT) stage((t + 2) % 3, t + 2);
    }

    const int pc = (head * 16 + qblk) * NCH + chunk;
    u16* orow = po + ((size_t)pc * 128 + (w * 32 + lm)) * 64;
#pragma unroll
    for (int g = 0; g < 4; ++g) {
        short4v pk0, pk1;
#pragma unroll
        for (int e = 0; e < 4; ++e) {
            pk0[e] = (short)f2bf(o0[g * 4 + e]);
            pk1[e] = (short)f2bf(o1[g * 4 + e]);
        }
        *(short4v*)(orow + g * 8 + hi * 4) = pk0;
        *(short4v*)(orow + 32 + g * 8 + hi * 4) = pk1;
    }
    if (hi == 0)
        pml[(size_t)pc * 128 + (w * 32 + lm)] = accl[0];
}

// ---------------- merge split-K partials -> ctx bf16 [B,S,H*64] ------------
__global__ __launch_bounds__(256)
void attn_merge(const u16* __restrict__ po, const float* __restrict__ pml,
                u16* __restrict__ ctx, int nch) {
    const int head = blockIdx.y;
    const int bb = head / HEADS, hh = head % HEADS;
    const int rl = threadIdx.x >> 4, dg = threadIdx.x & 15;
    const int s = blockIdx.x * 16 + rl;
    const int qb = s >> 7, qr = s & 127;
    const int pcb = (head * 16 + qb) * nch;

    float denom = 0.0f;
    float acc[4] = {0.0f, 0.0f, 0.0f, 0.0f};
#pragma unroll 4
    for (int c = 0; c < nch; ++c) {
        denom += pml[((size_t)(pcb + c)) * 128 + qr];
        const u16* op = po + (((size_t)(pcb + c) * 128 + qr) * 64) + dg * 4;
        short4v a = *(const short4v*)op;
#pragma unroll
        for (int e = 0; e < 4; ++e) acc[e] += bf2f((u16)a[e]);
    }
    float inv = 1.0f / denom;
    short4v r;
#pragma unroll
    for (int e = 0; e < 4; ++e) r[e] = (short)f2bf(acc[e] * inv);
    *(short4v*)(ctx + ((size_t)(bb * SS + s)) * D_MODEL + hh * DHEAD + dg * 4) = r;
}

// ---------------------------------------------------------------------------
extern "C" void kernel_launch(void* const* d_in, const int* in_sizes, int n_in,
                              void* d_out, int out_size, void* d_ws, size_t ws_size,
                              hipStream_t stream) {
    const int*   iterp  = (const int*)  d_in[0];
    const float* inputs = (const float*)d_in[2];
    const int*   mask   = (const int*)  d_in[3];
    const float* Wq = (const float*)d_in[4];
    const float* bq = (const float*)d_in[5];
    const float* Wk = (const float*)d_in[6];
    const float* bk = (const float*)d_in[7];
    const float* Wv = (const float*)d_in[8];
    const float* bv = (const float*)d_in[9];
    const float* Wo = (const float*)d_in[10];
    const float* bo = (const float*)d_in[11];
    const float* ln1g = (const float*)d_in[12];
    const float* ln1b = (const float*)d_in[13];
    const float* W1 = (const float*)d_in[14];
    const float* b1 = (const float*)d_in[15];
    const float* W2 = (const float*)d_in[16];
    const float* b2 = (const float*)d_in[17];
    const float* ln2g = (const float*)d_in[18];
    const float* ln2b = (const float*)d_in[19];
    float* outp = (float*)d_out;

    char* ws = (char*)d_ws;
    size_t off = 0;
    auto alloc = [&](size_t bytes) -> void* {
        void* p = ws + off;
        off += (bytes + 255) & ~(size_t)255;
        return p;
    };
    u16*   wqkv_t = (u16*)  alloc((size_t)2304 * 768 * 2);
    u16*   wo_t   = (u16*)  alloc((size_t)768 * 768 * 2);
    u16*   w1_t   = (u16*)  alloc((size_t)3072 * 768 * 2);
    u16*   w2_t   = (u16*)  alloc((size_t)768 * 3072 * 2);
    float* vzf    = (float*)alloc((size_t)MTOT * 4);        // valid01 fp32
    u16*   m01    = (u16*)  alloc((size_t)MTOT * 2);        // valid01 bf16
    u16*   xh     = (u16*)  alloc((size_t)MTOT * 768 * 2);  // x / h / attn l
    u16*   qb     = (u16*)  alloc((size_t)MTOT * 768 * 2);
    u16*   kbuf   = (u16*)  alloc((size_t)MTOT * 768 * 2);
    u16*   vtb    = (u16*)  alloc((size_t)MTOT * 768 * 2);
    u16*   ctxb   = (u16*)  alloc((size_t)MTOT * 768 * 2);
    float* outm   = (float*)alloc((size_t)MTOT * 768 * 4);  // 12.58 MB
    u16*   inter  = qb;  // reuse q|k|vt|ctx region

    // fp32 split-K partial buffer for the skinny GEMMs (Wo, FFN2): 25.2 MB.
    // NOTE: allocated immediately after outm -> outm..pfbuf is one contiguous
    // 37.8 MB span (sizes are 256-multiple), used as the QKV bf16 partial P.
    float* pfbuf = (float*)alloc((size_t)2 * MTOT * 768 * 4);
    const bool split_ok = (off <= ws_size);   // fallback if ws too small

    float* pml = (float*)xh;

    dim3 blk(256);
    transpose_cast4<<<dim3(24, 24, 4), blk, 0, stream>>>(
        Wq, Wk, Wv, Wo,
        wqkv_t, wqkv_t + 768 * 768, wqkv_t + 2 * 768 * 768, wo_t);
    transpose_cast<<<dim3(96, 24), blk, 0, stream>>>(W1, w1_t, 768, 3072);
    transpose_cast<<<dim3(24, 96), blk, 0, stream>>>(W2, w2_t, 3072, 768);
    maskprep<<<dim3(16), blk, 0, stream>>>(mask, vzf, m01, MTOT);

    // x = LN1(inputs) (skipped if iter==0), bf16
    ln_bf16<<<dim3(MTOT), blk, 0, stream>>>(inputs, ln1g, ln1b, xh, iterp, 1);

    // fused QKV projection — split-K=2 (grid 1152 = 4.5 blocks/CU candidates)
    // bf16 partials P alias outm+pfbuf (37.8 MB); reduce does bias/scale/
    // mask-zero + coalesced scatter (incl. v^T via LDS transpose).
    if (split_ok) {
        u16* P = (u16*)outm;
        gemm_bt<3><<<dim3(2304 / 128, MTOT / 128, 2), blk, 0, stream>>>(
            xh, wqkv_t, 768, 2304, nullptr, nullptr, nullptr, nullptr,
            nullptr, P, nullptr, nullptr);
        reduce_qkv<<<dim3(1536, 3), blk, 0, stream>>>(
            P, bq, bk, bv, vzf, qb, kbuf, vtb);
    } else {
        gemm_bt<0><<<dim3(2304 / 128, MTOT / 128), blk, 0, stream>>>(
            xh, wqkv_t, 768, 2304, bq, bk, bv, vzf, nullptr, qb, kbuf, vtb);
    }

    // flash attention: 4-wave blocks, ring-3, split-K=4
    if (split_ok) {
        u16* po = (u16*)pfbuf;
        attn_fwd6<4><<<dim3(16 * 4, BB * HEADS), blk, 0, stream>>>(
            qb, kbuf, vtb, m01, po, pml);
        attn_merge<<<dim3(SS / 16, BB * HEADS), blk, 0, stream>>>(po, pml, ctxb, 4);
    } else {
        u16* po = (u16*)outm;
        attn_fwd6<2><<<dim3(16 * 2, BB * HEADS), blk, 0, stream>>>(
            qb, kbuf, vtb, m01, po, pml);
        attn_merge<<<dim3(SS / 16, BB * HEADS), blk, 0, stream>>>(po, pml, ctxb, 2);
    }

    // out = ctx @ Wo + bo + inputs; h = LN2(out)
    if (split_ok) {
        gemm_bt<1><<<dim3(768 / 128, MTOT / 128, 2), blk, 0, stream>>>(
            ctxb, wo_t, 768, 768, nullptr, nullptr, nullptr, nullptr,
            pfbuf, nullptr, nullptr, nullptr);
        ln_fuse<<<dim3(MTOT), blk, 0, stream>>>(pfbuf, bo, inputs, ln2g, ln2b, outm, xh);
    } else {
        gemm_bt<1><<<dim3(768 / 128, MTOT / 128), blk, 0, stream>>>(
            ctxb, wo_t, 768, 768, bo, nullptr, nullptr, inputs, outm, nullptr, nullptr, nullptr);
        ln_bf16<<<dim3(MTOT), blk, 0, stream>>>(outm, ln2g, ln2b, xh, iterp, 0);
    }

    // inter = gelu(h @ W1 + b1), bf16  (768 blocks = 3/CU — CONTROL dispatch)
    gemm_bt<2><<<dim3(3072 / 128, MTOT / 128), blk, 0, stream>>>(
        xh, w1_t, 768, 3072, b1, nullptr, nullptr, nullptr, nullptr, inter, nullptr, nullptr);

    // d_out = inter @ W2 + b2 + out  (fp32)  — split-K=2 -> 384 blocks
    if (split_ok) {
        gemm_bt<1><<<dim3(768 / 128, MTOT / 128, 2), blk, 0, stream>>>(
            inter, w2_t, 3072, 768, nullptr, nullptr, nullptr, nullptr,
            pfbuf, nullptr, nullptr, nullptr);
        reduce_ks2<<<dim3(MTOT * 768 / 1024), blk, 0, stream>>>(pfbuf, b2, outm, outp, 768);
    } else {
        gemm_bt<1><<<dim3(768 / 128, MTOT / 128), blk, 0, stream>>>(
            inter, w2_t, 3072, 768, b2, nullptr, nullptr, outm, outp, nullptr, nullptr, nullptr);
    }
}

// Round 16
// 214.387 us; speedup vs baseline: 1.0210x; 1.0199x over previous
//
#include <hip/hip_runtime.h>
#include <hip/hip_bf16.h>
#include <stdint.h>

#define D_MODEL 768
#define HEADS   12
#define DHEAD   64
#define D_FF    3072
#define BB      2
#define SS      2048
#define MTOT    (BB*SS)   // 4096

typedef uint16_t u16;
typedef uint32_t u32;
typedef __attribute__((ext_vector_type(8))) short short8;
typedef __attribute__((ext_vector_type(4))) short short4v;
typedef __attribute__((ext_vector_type(4))) float f32x4;
typedef __attribute__((ext_vector_type(16))) float f32x16;
typedef __attribute__((ext_vector_type(2))) unsigned uint2v;

__device__ __forceinline__ u16 f2bf(float f) {
    union { float f; u32 u; } v; v.f = f;
    u32 r = v.u + 0x7fffu + ((v.u >> 16) & 1u);
    return (u16)(r >> 16);
}

__device__ __forceinline__ float bf2f(u16 u) {
    union { u32 u; float f; } v; v.u = ((u32)u) << 16;
    return v.f;
}

// raw v_exp_f32 (2^x): scores bounded |x|<~16, no OCML range-check expansion
__device__ __forceinline__ float exp2_fast(float x) {
#if __has_builtin(__builtin_amdgcn_exp2f)
    return __builtin_amdgcn_exp2f(x);
#else
    return exp2f(x);
#endif
}

// packed bf16 convert: dst = {bf16(a) lo, bf16(b) hi}  (T12 recipe)
__device__ __forceinline__ u32 cvtpk(float a, float b) {
    u32 r;
    asm("v_cvt_pk_bf16_f32 %0, %1, %2" : "=v"(r) : "v"(a), "v"(b));
    return r;
}

// half-wave exchange: a' = [a.row0, b.row0], b' = [a.row1, b.row1]
__device__ __forceinline__ void plswap(u32& a, u32& b, int hi) {
#if __has_builtin(__builtin_amdgcn_permlane32_swap)
    uint2v r = __builtin_amdgcn_permlane32_swap(a, b, false, false);
    a = r[0]; b = r[1];
#else
    u32 ax = (u32)__shfl_xor((int)a, 32), bx = (u32)__shfl_xor((int)b, 32);
    u32 na = hi ? bx : a, nb = hi ? b : ax;
    a = na; b = nb;
#endif
}

__device__ __forceinline__ void gload16(const void* g, void* l) {
    __builtin_amdgcn_global_load_lds(
        (const __attribute__((address_space(1))) u32*)g,
        (__attribute__((address_space(3))) u32*)l, 16, 0, 0);
}

#define MFMA16(a, b, c) __builtin_amdgcn_mfma_f32_16x16x32_bf16((a), (b), (c), 0, 0, 0)
#define MFMA32(a, b, c) __builtin_amdgcn_mfma_f32_32x32x16_bf16((a), (b), (c), 0, 0, 0)

// tanh-GELU via the exact sigmoid identity: 0.5x(1+tanh(z)) = x*sigmoid(2z).
// In base-2: gelu(x) = x / (1 + exp2(-(2c*log2e)x - (2c*0.044715*log2e)x^3)),
// c = sqrt(2/pi). ~7 VALU + 1 v_exp_f32 vs ~30 for OCML tanhf.
__device__ __forceinline__ float gelu_tanh_f(float x) {
    const float A = 2.302208236477496f;    // 2c * log2(e)
    const float B = 0.10294344415603161f;  // 2c * 0.044715 * log2(e)
    float t = -x * (A + B * x * x);
    return x / (1.0f + exp2_fast(t));
}

// ---------------- weight transpose + cast: W[R][C] fp32 -> Wt[C][R] bf16 ----
__global__ __launch_bounds__(256)
void transpose_cast(const float* __restrict__ W, u16* __restrict__ Wt, int R, int C) {
    __shared__ float tile[32][33];
    int bx = blockIdx.x, by = blockIdx.y;
    int x = threadIdx.x & 31, y0 = threadIdx.x >> 5;
#pragma unroll
    for (int i = 0; i < 4; ++i) {
        int y = y0 + i * 8;
        tile[y][x] = W[(size_t)(by * 32 + y) * C + bx * 32 + x];
    }
    __syncthreads();
#pragma unroll
    for (int i = 0; i < 4; ++i) {
        int y = y0 + i * 8;
        Wt[(size_t)(bx * 32 + y) * R + by * 32 + x] = f2bf(tile[x][y]);
    }
}

// batched 768x768 transpose: z selects among 4 weight matrices
__global__ __launch_bounds__(256)
void transpose_cast4(const float* __restrict__ W0, const float* __restrict__ W1,
                     const float* __restrict__ W2, const float* __restrict__ W3,
                     u16* __restrict__ T0, u16* __restrict__ T1,
                     u16* __restrict__ T2, u16* __restrict__ T3) {
    const int z = blockIdx.z;
    const float* W = z == 0 ? W0 : z == 1 ? W1 : z == 2 ? W2 : W3;
    u16*         T = z == 0 ? T0 : z == 1 ? T1 : z == 2 ? T2 : T3;
    __shared__ float tile[32][33];
    int bx = blockIdx.x, by = blockIdx.y;
    int x = threadIdx.x & 31, y0 = threadIdx.x >> 5;
#pragma unroll
    for (int i = 0; i < 4; ++i) {
        int y = y0 + i * 8;
        tile[y][x] = W[(size_t)(by * 32 + y) * 768 + bx * 32 + x];
    }
    __syncthreads();
#pragma unroll
    for (int i = 0; i < 4; ++i) {
        int y = y0 + i * 8;
        T[(size_t)(bx * 32 + y) * 768 + by * 32 + x] = f2bf(tile[x][y]);
    }
}

// ---- mask (int 0/1): masked -> valid01 = 0 (float for V-zeroing, bf16 frag)
__global__ void maskprep(const int* __restrict__ m, float* __restrict__ vz,
                         u16* __restrict__ m01, int n) {
    int i = blockIdx.x * 256 + threadIdx.x;
    if (i < n) {
        float v = m[i] ? 0.0f : 1.0f;
        vz[i] = v;
        m01[i] = f2bf(v);
    }
}

// ---------------- LayerNorm fp32 -> bf16 (optionally skipped if iter==0) ----
__global__ __launch_bounds__(256)
void ln_bf16(const float* __restrict__ in, const float* __restrict__ g,
             const float* __restrict__ bta, u16* __restrict__ out,
             const int* __restrict__ iterp, int checkIter) {
    int row = blockIdx.x, tid = threadIdx.x;
    const float* x = in + (size_t)row * D_MODEL;
    float v0 = x[tid], v1 = x[tid + 256], v2 = x[tid + 512];
    float s = v0 + v1 + v2;
    float s2 = v0 * v0 + v1 * v1 + v2 * v2;
#pragma unroll
    for (int o = 1; o < 64; o <<= 1) { s += __shfl_xor(s, o); s2 += __shfl_xor(s2, o); }
    __shared__ float sh[8];
    int w = tid >> 6;
    if ((tid & 63) == 0) { sh[w] = s; sh[4 + w] = s2; }
    __syncthreads();
    s = sh[0] + sh[1] + sh[2] + sh[3];
    s2 = sh[4] + sh[5] + sh[6] + sh[7];
    float mu = s * (1.0f / 768.0f);
    float var = s2 * (1.0f / 768.0f) - mu * mu;
    float rstd = rsqrtf(var + 1e-6f);
    bool skip = checkIter && (iterp[0] == 0);
    u16* o0 = out + (size_t)row * D_MODEL;
    if (skip) {
        o0[tid] = f2bf(v0); o0[tid + 256] = f2bf(v1); o0[tid + 512] = f2bf(v2);
    } else {
        o0[tid]       = f2bf((v0 - mu) * rstd * g[tid]       + bta[tid]);
        o0[tid + 256] = f2bf((v1 - mu) * rstd * g[tid + 256] + bta[tid + 256]);
        o0[tid + 512] = f2bf((v2 - mu) * rstd * g[tid + 512] + bta[tid + 512]);
    }
}

// ------- fused split-K reduce + residual + LN2:  v = pf0+pf1+bias+res;
//         outm = v (fp32 residual); out = bf16(LN(v))
__global__ __launch_bounds__(256)
void ln_fuse(const float* __restrict__ pf, const float* __restrict__ bias,
             const float* __restrict__ res, const float* __restrict__ g,
             const float* __restrict__ bta, float* __restrict__ outm,
             u16* __restrict__ out) {
    int row = blockIdx.x, tid = threadIdx.x;
    size_t i0 = (size_t)row * D_MODEL + tid;
    const float* pf1 = pf + (size_t)MTOT * D_MODEL;
    float v0 = pf[i0]       + pf1[i0]       + bias[tid]       + res[i0];
    float v1 = pf[i0 + 256] + pf1[i0 + 256] + bias[tid + 256] + res[i0 + 256];
    float v2 = pf[i0 + 512] + pf1[i0 + 512] + bias[tid + 512] + res[i0 + 512];
    outm[i0] = v0; outm[i0 + 256] = v1; outm[i0 + 512] = v2;
    float s = v0 + v1 + v2;
    float s2 = v0 * v0 + v1 * v1 + v2 * v2;
#pragma unroll
    for (int o = 1; o < 64; o <<= 1) { s += __shfl_xor(s, o); s2 += __shfl_xor(s2, o); }
    __shared__ float sh[8];
    int w = tid >> 6;
    if ((tid & 63) == 0) { sh[w] = s; sh[4 + w] = s2; }
    __syncthreads();
    s = sh[0] + sh[1] + sh[2] + sh[3];
    s2 = sh[4] + sh[5] + sh[6] + sh[7];
    float mu = s * (1.0f / 768.0f);
    float var = s2 * (1.0f / 768.0f) - mu * mu;
    float rstd = rsqrtf(var + 1e-6f);
    u16* o0 = out + (size_t)row * D_MODEL;
    o0[tid]       = f2bf((v0 - mu) * rstd * g[tid]       + bta[tid]);
    o0[tid + 256] = f2bf((v1 - mu) * rstd * g[tid + 256] + bta[tid + 256]);
    o0[tid + 512] = f2bf((v2 - mu) * rstd * g[tid + 512] + bta[tid + 512]);
}

// ---------------- GEMM  C = A[M][K] * Bt[N][K]^T  (bf16 in, fp32 acc) -------
// 128x128 tile, BK=32, ring-3 LDS (best measured main loop).
// MODE 0: QKV epilogue scatter (fallback path, no split-K)
// MODE 1: outF = acc + bias + res (fp32)  [raw fp32 partials if gridDim.z>1]
// MODE 2: outB = bf16(gelu(acc + bias))
// MODE 3: raw bf16 partial: oq[(z*MTOT+row)*N+col] = bf16(acc)  (QKV split-K)
template <int MODE>
__global__ __launch_bounds__(256, 3)
void gemm_bt(const u16* __restrict__ A, const u16* __restrict__ Bt,
             int K, int N,
             const float* __restrict__ bias0, const float* __restrict__ bias1,
             const float* __restrict__ bias2,
             const float* __restrict__ res,
             float* __restrict__ outF, u16* __restrict__ oq,
             u16* __restrict__ ok, u16* __restrict__ ov) {
    __shared__ __align__(16) u16 aT[3][128 * 32];
    __shared__ __align__(16) u16 bT[3][128 * 32];
    const int tid = threadIdx.x;
    const int lane = tid & 63;
    const int w = tid >> 6;
    const int wr = w >> 1, wc = w & 1;
    const int lm = lane & 15, lq = lane >> 4;
    const int bm = blockIdx.y, bn = blockIdx.x;
    const int kzlen = K / gridDim.z;
    const int kbeg = blockIdx.z * kzlen;
    const int nsteps = kzlen >> 5;

    const u16* Abase = A  + (size_t)(bm * 128) * K + kbeg;
    const u16* Bbase = Bt + (size_t)(bn * 128) * K + kbeg;

    auto stage = [&](int buf, int t) {
        int k0 = t * 32;
#pragma unroll
        for (int j = 0; j < 2; ++j) {
            int d = j * 256 + tid;          // 16B-chunk index within tile
            int row = d >> 2, p = d & 3;
            int src = (p ^ (row & 3)) * 8;
            gload16(Abase + (size_t)row * K + k0 + src, aT[buf] + (j * 256 + w * 64) * 8);
            gload16(Bbase + (size_t)row * K + k0 + src, bT[buf] + (j * 256 + w * 64) * 8);
        }
    };

    f32x4 acc[4][4] = {};
    stage(0, 0);
    if (nsteps > 1) stage(1, 1);

#pragma unroll 1
    for (int t = 0; t < nsteps; ++t) {
        if (t + 1 < nsteps) asm volatile("s_waitcnt vmcnt(4)" ::: "memory");
        else                asm volatile("s_waitcnt vmcnt(0)" ::: "memory");
        __syncthreads();
        const u16* Ab = aT[t % 3];
        const u16* Bb = bT[t % 3];
        short8 av[4], bv[4];
#pragma unroll
        for (int m = 0; m < 4; ++m) {
            int row = wr * 64 + m * 16 + lm;
            av[m] = *(const short8*)(Ab + row * 32 + ((lq ^ (row & 3)) * 8));
        }
#pragma unroll
        for (int n = 0; n < 4; ++n) {
            int row = wc * 64 + n * 16 + lm;
            bv[n] = *(const short8*)(Bb + row * 32 + ((lq ^ (row & 3)) * 8));
        }
#pragma unroll
        for (int m = 0; m < 4; ++m)
#pragma unroll
            for (int n = 0; n < 4; ++n)
                acc[m][n] = MFMA16(av[m], bv[n], acc[m][n]);
        if (t + 2 < nsteps) stage((t + 2) % 3, t + 2);   // refill ring
    }

#pragma unroll
    for (int m = 0; m < 4; ++m) {
#pragma unroll
        for (int n = 0; n < 4; ++n) {
            int col = bn * 128 + wc * 64 + n * 16 + lm;
#pragma unroll
            for (int r = 0; r < 4; ++r) {
                int row = bm * 128 + wr * 64 + m * 16 + lq * 4 + r;
                float v = acc[m][n][r];
                if (MODE == 0) {
                    int proj = col / D_MODEL;
                    int d = col - proj * D_MODEL;
                    int hh = d >> 6, dhi = d & 63;
                    int bb = row >> 11, sIdx = row & 2047;
                    if (proj == 0) {
                        v = (v + bias0[d]) * 0.18033688011112042f;
                        oq[((size_t)(bb * HEADS + hh) * SS + sIdx) * DHEAD + dhi] = f2bf(v);
                    } else if (proj == 1) {
                        v = v + bias1[d];
                        ok[((size_t)(bb * HEADS + hh) * SS + sIdx) * DHEAD + dhi] = f2bf(v);
                    } else {
                        v = (v + bias2[d]) * res[row];
                        ov[((size_t)(bb * HEADS + hh) * DHEAD + dhi) * SS + sIdx] = f2bf(v);
                    }
                } else if (MODE == 1) {
                    if (gridDim.z > 1) {
                        outF[((size_t)blockIdx.z * MTOT + row) * N + col] = v;
                    } else {
                        size_t idx = (size_t)row * N + col;
                        outF[idx] = v + bias0[col] + res[idx];
                    }
                } else if (MODE == 2) {
                    float t2 = v + bias0[col];
                    oq[(size_t)row * N + col] = f2bf(gelu_tanh_f(t2));
                } else {   // MODE 3: raw bf16 partial
                    oq[((size_t)blockIdx.z * MTOT + row) * N + col] = f2bf(v);
                }
            }
        }
    }
}

// ---------------- QKV split-K reduce + epilogue scatter ---------------------
// P = bf16 partials [2][MTOT][2304]. Zones (blockIdx.y): 0=q, 1=k, 2=v^T.
__global__ __launch_bounds__(256)
void reduce_qkv(const u16* __restrict__ P,
                const float* __restrict__ bq, const float* __restrict__ bk,
                const float* __restrict__ bv, const float* __restrict__ vz,
                u16* __restrict__ qq, u16* __restrict__ kk,
                u16* __restrict__ vt) {
    const int zone = blockIdx.y;
    const int tid = threadIdx.x;
    const u16* P1 = P + (size_t)MTOT * 2304;

    if (zone < 2) {
        // thread handles 8 consecutive cols of one row; 16B loads/stores
        int idx = blockIdx.x * 256 + tid;            // < 4096*96
        int row = idx / 96;
        int c8  = idx - row * 96;
        int col = zone * 768 + c8 * 8;
        short8 a = *(const short8*)(P  + (size_t)row * 2304 + col);
        short8 b = *(const short8*)(P1 + (size_t)row * 2304 + col);
        const float* bias = zone ? bk : bq;
        union { u16 u[8]; short8 s; } o;
#pragma unroll
        for (int e = 0; e < 8; ++e) {
            float v = bf2f((u16)a[e]) + bf2f((u16)b[e]) + bias[c8 * 8 + e];
            if (zone == 0) v *= 0.18033688011112042f;   // 1/8 * log2(e)
            o.u[e] = f2bf(v);
        }
        int d = c8 * 8, hh = d >> 6, dhi = d & 63;
        int bb = row >> 11, s = row & 2047;
        u16* dst = (zone ? kk : qq) +
                   ((size_t)(bb * HEADS + hh) * SS + s) * DHEAD + dhi;
        *(short8*)dst = o.s;
    } else {
        // v^T via LDS transpose: 64x64 tile of (row, vcol) space
        if (blockIdx.x >= 768) return;               // 64 row-tiles x 12 heads
        __shared__ u16 tile[64][72];
        int tr = blockIdx.x / 12, tc = blockIdx.x - tr * 12;
        int r0 = tr * 64;
#pragma unroll
        for (int p = 0; p < 2; ++p) {
            int lr = p * 32 + (tid >> 3);            // 0..63 local row
            int coff = (tid & 7) * 8;
            int row = r0 + lr;
            const u16* p0 = P + (size_t)row * 2304 + 1536 + tc * 64 + coff;
            short8 a = *(const short8*)p0;
            short8 b = *(const short8*)(p0 + (size_t)MTOT * 2304);
            float zf = vz[row];
#pragma unroll
            for (int e = 0; e < 8; ++e) {
                float v = (bf2f((u16)a[e]) + bf2f((u16)b[e]) +
                           bv[tc * 64 + coff + e]) * zf;
                tile[lr][coff + e] = f2bf(v);
            }
        }
        __syncthreads();
        int c = tid >> 2, sg = tid & 3;              // c: dhi, sg: 16-row group
        union { u16 u[16]; f32x4 v4[4]; } buf;
#pragma unroll
        for (int i = 0; i < 16; ++i) buf.u[i] = tile[sg * 16 + i][c];
        int bb = r0 >> 11;
        int s0 = (r0 & 2047) + sg * 16;
        u16* dst = vt + ((size_t)(bb * HEADS + tc) * DHEAD + c) * SS + s0;
        *(f32x4*)dst = buf.v4[0];
        *(f32x4*)(dst + 8) = buf.v4[1];
    }
}

// ---------------- split-K=2 reduce: out = pf[0] + pf[1] + bias + res --------
__global__ __launch_bounds__(256)
void reduce_ks2(const float* __restrict__ pf, const float* __restrict__ bias,
                const float* __restrict__ res, float* __restrict__ out, int N) {
    size_t i = ((size_t)blockIdx.x * 256 + threadIdx.x) * 4;
    f32x4 s0 = *(const f32x4*)(pf + i);
    f32x4 s1 = *(const f32x4*)(pf + (size_t)MTOT * N + i);
    int col = (int)(i % (size_t)N);
    f32x4 b = *(const f32x4*)(bias + col);
    f32x4 r = *(const f32x4*)(res + i);
    f32x4 o;
#pragma unroll
    for (int e = 0; e < 4; ++e) o[e] = s0[e] + s1[e] + b[e] + r[e];
    *(f32x4*)(out + i) = o;
}

// ---------------- flash attention: 4-wave + ring-3 --------------------------
// Max-free softmax; V rows pre-zeroed for masked keys; l = MFMA(mask01, P).
template <int NCH>
__global__ __launch_bounds__(256, 3)
void attn_fwd6(const u16* __restrict__ q, const u16* __restrict__ k,
               const u16* __restrict__ vtg, const u16* __restrict__ m01g,
               u16* __restrict__ po, float* __restrict__ pml) {
    constexpr int KLEN = SS / NCH;      // keys per chunk
    constexpr int KT   = KLEN / 64;     // 64-key tiles per chunk
    __shared__ __align__(16) u16 kls[3][64 * 64];   // [key][d], XOR-swizzled
    __shared__ __align__(16) u16 vls[3][64 * 64];   // [d][key], XOR-swizzled
    __shared__ __align__(16) u16 m01l[KLEN];        // valid01 bf16 chunk

    const int tid = threadIdx.x, lane = tid & 63, w = tid >> 6;
    const int lm = lane & 31, hi = lane >> 5;
    const int head = blockIdx.y;
    const int qblk = blockIdx.x / NCH, chunk = blockIdx.x % NCH;
    const int q0 = qblk * 128;
    const int k0 = chunk * KLEN;

    const u16* qbase = q + (size_t)head * SS * DHEAD;
    const u16* kbase = k + (size_t)head * SS * DHEAD;
    const u16* vbase = vtg + (size_t)head * DHEAD * SS;
    const u16* m01row = m01g + (head / HEADS) * SS;

    short8 qf[4];
    const int qrow = q0 + w * 32 + lm;
#pragma unroll
    for (int c = 0; c < 4; ++c)
        qf[c] = *(const short8*)(qbase + (size_t)qrow * DHEAD + c * 16 + hi * 8);

    if (tid < KLEN / 8)
        gload16(m01row + k0 + (size_t)tid * 8, m01l + (size_t)(tid >> 6) * 64 * 8);

    auto stage = [&](int buf, int t) {
#pragma unroll
        for (int j = 0; j < 2; ++j) {
            int c = j * 256 + tid;
            int row = c >> 3, jj = c & 7;
            gload16(kbase + (size_t)(k0 + t * 64 + row) * DHEAD + ((jj ^ (row & 7)) * 8),
                    kls[buf] + (j * 256 + w * 64) * 8);
            gload16(vbase + (size_t)row * SS + k0 + t * 64 + ((jj ^ (row & 7)) * 8),
                    vls[buf] + (j * 256 + w * 64) * 8);
        }
    };
    stage(0, 0);
    if (KT > 1) stage(1, 1);

    f32x16 o0 = {}, o1 = {}, accl = {};

#pragma unroll 1
    for (int t = 0; t < KT; ++t) {
        if (t + 1 < KT) asm volatile("s_waitcnt vmcnt(4)" ::: "memory");
        else            asm volatile("s_waitcnt vmcnt(0)" ::: "memory");
        __syncthreads();
        const u16* kb = kls[t % 3];
        const u16* vb = vls[t % 3];
#pragma unroll
        for (int s = 0; s < 2; ++s) {
            short8 av[4];
#pragma unroll
            for (int c = 0; c < 4; ++c)
                av[c] = *(const short8*)(kb + (s * 32 + lm) * 64 + (((c * 2 + hi) ^ (lm & 7)) * 8));
            short8 vf[4];
#pragma unroll
            for (int kc = 0; kc < 2; ++kc)
#pragma unroll
                for (int df = 0; df < 2; ++df)
                    vf[kc * 2 + df] = *(const short8*)(vb + (df * 32 + lm) * 64 +
                                                       (((s * 4 + kc * 2 + hi) ^ (lm & 7)) * 8));
            short8 mf0 = *(const short8*)(m01l + t * 64 + s * 32 + hi * 8);
            short8 mf1 = *(const short8*)(m01l + t * 64 + s * 32 + 16 + hi * 8);

            f32x16 st = {};
#pragma unroll
            for (int c = 0; c < 4; ++c) st = MFMA32(av[c], qf[c], st);

            float p[16];
#pragma unroll
            for (int r = 0; r < 16; ++r) p[r] = exp2_fast(st[r]);

            u32 W[8];
#pragma unroll
            for (int t8 = 0; t8 < 8; ++t8) W[t8] = cvtpk(p[2 * t8], p[2 * t8 + 1]);
            union { u32 wd[4]; short8 s8; } pf0, pf1;
            u32 a0w = W[0], b0w = W[2]; plswap(a0w, b0w, hi);
            u32 a1w = W[1], b1w = W[3]; plswap(a1w, b1w, hi);
            u32 a2w = W[4], b2w = W[6]; plswap(a2w, b2w, hi);
            u32 a3w = W[5], b3w = W[7]; plswap(a3w, b3w, hi);
            pf0.wd[0] = a0w; pf0.wd[1] = a1w; pf0.wd[2] = b0w; pf0.wd[3] = b1w;
            pf1.wd[0] = a2w; pf1.wd[1] = a3w; pf1.wd[2] = b2w; pf1.wd[3] = b3w;

            accl = MFMA32(mf0, pf0.s8, accl);
            accl = MFMA32(mf1, pf1.s8, accl);
            o0 = MFMA32(vf[0], pf0.s8, o0);
            o1 = MFMA32(vf[1], pf0.s8, o1);
            o0 = MFMA32(vf[2], pf1.s8, o0);
            o1 = MFMA32(vf[3], pf1.s8, o1);
        }
        if (t + 2 < KT) stage((t + 2) % 3, t + 2);
    }

    const int pc = (head * 16 + qblk) * NCH + chunk;
    u16* orow = po + ((size_t)pc * 128 + (w * 32 + lm)) * 64;
#pragma unroll
    for (int g = 0; g < 4; ++g) {
        short4v pk0, pk1;
#pragma unroll
        for (int e = 0; e < 4; ++e) {
            pk0[e] = (short)f2bf(o0[g * 4 + e]);
            pk1[e] = (short)f2bf(o1[g * 4 + e]);
        }
        *(short4v*)(orow + g * 8 + hi * 4) = pk0;
        *(short4v*)(orow + 32 + g * 8 + hi * 4) = pk1;
    }
    if (hi == 0)
        pml[(size_t)pc * 128 + (w * 32 + lm)] = accl[0];
}

// ---------------- merge split-K partials -> ctx bf16 [B,S,H*64] ------------
__global__ __launch_bounds__(256)
void attn_merge(const u16* __restrict__ po, const float* __restrict__ pml,
                u16* __restrict__ ctx, int nch) {
    const int head = blockIdx.y;
    const int bb = head / HEADS, hh = head % HEADS;
    const int rl = threadIdx.x >> 4, dg = threadIdx.x & 15;
    const int s = blockIdx.x * 16 + rl;
    const int qb = s >> 7, qr = s & 127;
    const int pcb = (head * 16 + qb) * nch;

    float denom = 0.0f;
    float acc[4] = {0.0f, 0.0f, 0.0f, 0.0f};
#pragma unroll 4
    for (int c = 0; c < nch; ++c) {
        denom += pml[((size_t)(pcb + c)) * 128 + qr];
        const u16* op = po + (((size_t)(pcb + c) * 128 + qr) * 64) + dg * 4;
        short4v a = *(const short4v*)op;
#pragma unroll
        for (int e = 0; e < 4; ++e) acc[e] += bf2f((u16)a[e]);
    }
    float inv = 1.0f / denom;
    short4v r;
#pragma unroll
    for (int e = 0; e < 4; ++e) r[e] = (short)f2bf(acc[e] * inv);
    *(short4v*)(ctx + ((size_t)(bb * SS + s)) * D_MODEL + hh * DHEAD + dg * 4) = r;
}

// ---------------------------------------------------------------------------
extern "C" void kernel_launch(void* const* d_in, const int* in_sizes, int n_in,
                              void* d_out, int out_size, void* d_ws, size_t ws_size,
                              hipStream_t stream) {
    const int*   iterp  = (const int*)  d_in[0];
    const float* inputs = (const float*)d_in[2];
    const int*   mask   = (const int*)  d_in[3];
    const float* Wq = (const float*)d_in[4];
    const float* bq = (const float*)d_in[5];
    const float* Wk = (const float*)d_in[6];
    const float* bk = (const float*)d_in[7];
    const float* Wv = (const float*)d_in[8];
    const float* bv = (const float*)d_in[9];
    const float* Wo = (const float*)d_in[10];
    const float* bo = (const float*)d_in[11];
    const float* ln1g = (const float*)d_in[12];
    const float* ln1b = (const float*)d_in[13];
    const float* W1 = (const float*)d_in[14];
    const float* b1 = (const float*)d_in[15];
    const float* W2 = (const float*)d_in[16];
    const float* b2 = (const float*)d_in[17];
    const float* ln2g = (const float*)d_in[18];
    const float* ln2b = (const float*)d_in[19];
    float* outp = (float*)d_out;

    char* ws = (char*)d_ws;
    size_t off = 0;
    auto alloc = [&](size_t bytes) -> void* {
        void* p = ws + off;
        off += (bytes + 255) & ~(size_t)255;
        return p;
    };
    u16*   wqkv_t = (u16*)  alloc((size_t)2304 * 768 * 2);
    u16*   wo_t   = (u16*)  alloc((size_t)768 * 768 * 2);
    u16*   w1_t   = (u16*)  alloc((size_t)3072 * 768 * 2);
    u16*   w2_t   = (u16*)  alloc((size_t)768 * 3072 * 2);
    float* vzf    = (float*)alloc((size_t)MTOT * 4);        // valid01 fp32
    u16*   m01    = (u16*)  alloc((size_t)MTOT * 2);        // valid01 bf16
    u16*   xh     = (u16*)  alloc((size_t)MTOT * 768 * 2);  // x / h / attn l
    u16*   qb     = (u16*)  alloc((size_t)MTOT * 768 * 2);
    u16*   kbuf   = (u16*)  alloc((size_t)MTOT * 768 * 2);
    u16*   vtb    = (u16*)  alloc((size_t)MTOT * 768 * 2);
    u16*   ctxb   = (u16*)  alloc((size_t)MTOT * 768 * 2);
    float* outm   = (float*)alloc((size_t)MTOT * 768 * 4);  // 12.58 MB
    u16*   inter  = qb;  // reuse q|k|vt|ctx region

    // fp32 split-K partial buffer for the skinny GEMMs (Wo, FFN2): 25.2 MB.
    // Allocated right after outm -> contiguous 37.8 MB span = QKV bf16 P.
    float* pfbuf = (float*)alloc((size_t)2 * MTOT * 768 * 4);
    const bool split_ok = (off <= ws_size);   // fallback if ws too small

    float* pml = (float*)xh;

    dim3 blk(256);
    transpose_cast4<<<dim3(24, 24, 4), blk, 0, stream>>>(
        Wq, Wk, Wv, Wo,
        wqkv_t, wqkv_t + 768 * 768, wqkv_t + 2 * 768 * 768, wo_t);
    transpose_cast<<<dim3(96, 24), blk, 0, stream>>>(W1, w1_t, 768, 3072);
    transpose_cast<<<dim3(24, 96), blk, 0, stream>>>(W2, w2_t, 3072, 768);
    maskprep<<<dim3(16), blk, 0, stream>>>(mask, vzf, m01, MTOT);

    // x = LN1(inputs) (skipped if iter==0), bf16
    ln_bf16<<<dim3(MTOT), blk, 0, stream>>>(inputs, ln1g, ln1b, xh, iterp, 1);

    // fused QKV projection — split-K=2 (grid 1152)
    if (split_ok) {
        u16* P = (u16*)outm;
        gemm_bt<3><<<dim3(2304 / 128, MTOT / 128, 2), blk, 0, stream>>>(
            xh, wqkv_t, 768, 2304, nullptr, nullptr, nullptr, nullptr,
            nullptr, P, nullptr, nullptr);
        reduce_qkv<<<dim3(1536, 3), blk, 0, stream>>>(
            P, bq, bk, bv, vzf, qb, kbuf, vtb);
    } else {
        gemm_bt<0><<<dim3(2304 / 128, MTOT / 128), blk, 0, stream>>>(
            xh, wqkv_t, 768, 2304, bq, bk, bv, vzf, nullptr, qb, kbuf, vtb);
    }

    // flash attention: 4-wave blocks, ring-3, split-K=4
    if (split_ok) {
        u16* po = (u16*)pfbuf;
        attn_fwd6<4><<<dim3(16 * 4, BB * HEADS), blk, 0, stream>>>(
            qb, kbuf, vtb, m01, po, pml);
        attn_merge<<<dim3(SS / 16, BB * HEADS), blk, 0, stream>>>(po, pml, ctxb, 4);
    } else {
        u16* po = (u16*)outm;
        attn_fwd6<2><<<dim3(16 * 2, BB * HEADS), blk, 0, stream>>>(
            qb, kbuf, vtb, m01, po, pml);
        attn_merge<<<dim3(SS / 16, BB * HEADS), blk, 0, stream>>>(po, pml, ctxb, 2);
    }

    // out = ctx @ Wo + bo + inputs; h = LN2(out)
    if (split_ok) {
        gemm_bt<1><<<dim3(768 / 128, MTOT / 128, 2), blk, 0, stream>>>(
            ctxb, wo_t, 768, 768, nullptr, nullptr, nullptr, nullptr,
            pfbuf, nullptr, nullptr, nullptr);
        ln_fuse<<<dim3(MTOT), blk, 0, stream>>>(pfbuf, bo, inputs, ln2g, ln2b, outm, xh);
    } else {
        gemm_bt<1><<<dim3(768 / 128, MTOT / 128), blk, 0, stream>>>(
            ctxb, wo_t, 768, 768, bo, nullptr, nullptr, inputs, outm, nullptr, nullptr, nullptr);
        ln_bf16<<<dim3(MTOT), blk, 0, stream>>>(outm, ln2g, ln2b, xh, iterp, 0);
    }

    // inter = gelu(h @ W1 + b1), bf16  (768 blocks)
    gemm_bt<2><<<dim3(3072 / 128, MTOT / 128), blk, 0, stream>>>(
        xh, w1_t, 768, 3072, b1, nullptr, nullptr, nullptr, nullptr, inter, nullptr, nullptr);

    // d_out = inter @ W2 + b2 + out  (fp32)  — split-K=2 -> 384 blocks
    if (split_ok) {
        gemm_bt<1><<<dim3(768 / 128, MTOT / 128, 2), blk, 0, stream>>>(
            inter, w2_t, 3072, 768, nullptr, nullptr, nullptr, nullptr,
            pfbuf, nullptr, nullptr, nullptr);
        reduce_ks2<<<dim3(MTOT * 768 / 1024), blk, 0, stream>>>(pfbuf, b2, outm, outp, 768);
    } else {
        gemm_bt<1><<<dim3(768 / 128, MTOT / 128), blk, 0, stream>>>(
            inter, w2_t, 3072, 768, b2, nullptr, nullptr, outm, outp, nullptr, nullptr, nullptr);
    }
}

// Round 17
// 210.047 us; speedup vs baseline: 1.0421x; 1.0207x over previous
//
#include <hip/hip_runtime.h>
#include <hip/hip_bf16.h>
#include <stdint.h>

#define D_MODEL 768
#define HEADS   12
#define DHEAD   64
#define D_FF    3072
#define BB      2
#define SS      2048
#define MTOT    (BB*SS)   // 4096

typedef uint16_t u16;
typedef uint32_t u32;
typedef __attribute__((ext_vector_type(8))) short short8;
typedef __attribute__((ext_vector_type(4))) short short4v;
typedef __attribute__((ext_vector_type(4))) float f32x4;
typedef __attribute__((ext_vector_type(16))) float f32x16;
typedef __attribute__((ext_vector_type(2))) unsigned uint2v;

__device__ __forceinline__ u16 f2bf(float f) {
    union { float f; u32 u; } v; v.f = f;
    u32 r = v.u + 0x7fffu + ((v.u >> 16) & 1u);
    return (u16)(r >> 16);
}

__device__ __forceinline__ float bf2f(u16 u) {
    union { u32 u; float f; } v; v.u = ((u32)u) << 16;
    return v.f;
}

// raw v_exp_f32 (2^x): scores bounded |x|<~16, no OCML range-check expansion
__device__ __forceinline__ float exp2_fast(float x) {
#if __has_builtin(__builtin_amdgcn_exp2f)
    return __builtin_amdgcn_exp2f(x);
#else
    return exp2f(x);
#endif
}

// packed bf16 convert: dst = {bf16(a) lo, bf16(b) hi}  (T12 recipe)
__device__ __forceinline__ u32 cvtpk(float a, float b) {
    u32 r;
    asm("v_cvt_pk_bf16_f32 %0, %1, %2" : "=v"(r) : "v"(a), "v"(b));
    return r;
}

// half-wave exchange: a' = [a.row0, b.row0], b' = [a.row1, b.row1]
__device__ __forceinline__ void plswap(u32& a, u32& b, int hi) {
#if __has_builtin(__builtin_amdgcn_permlane32_swap)
    uint2v r = __builtin_amdgcn_permlane32_swap(a, b, false, false);
    a = r[0]; b = r[1];
#else
    u32 ax = (u32)__shfl_xor((int)a, 32), bx = (u32)__shfl_xor((int)b, 32);
    u32 na = hi ? bx : a, nb = hi ? b : ax;
    a = na; b = nb;
#endif
}

__device__ __forceinline__ void gload16(const void* g, void* l) {
    __builtin_amdgcn_global_load_lds(
        (const __attribute__((address_space(1))) u32*)g,
        (__attribute__((address_space(3))) u32*)l, 16, 0, 0);
}

#define MFMA16(a, b, c) __builtin_amdgcn_mfma_f32_16x16x32_bf16((a), (b), (c), 0, 0, 0)
#define MFMA32(a, b, c) __builtin_amdgcn_mfma_f32_32x32x16_bf16((a), (b), (c), 0, 0, 0)

// tanh-GELU via the exact sigmoid identity: 0.5x(1+tanh(z)) = x*sigmoid(2z).
__device__ __forceinline__ float gelu_tanh_f(float x) {
    const float A = 2.302208236477496f;    // 2c * log2(e)
    const float B = 0.10294344415603161f;  // 2c * 0.044715 * log2(e)
    float t = -x * (A + B * x * x);
    return x / (1.0f + exp2_fast(t));
}

// ---------------- weight transpose + cast: W[R][C] fp32 -> Wt[C][R] bf16 ----
__global__ __launch_bounds__(256)
void transpose_cast(const float* __restrict__ W, u16* __restrict__ Wt, int R, int C) {
    __shared__ float tile[32][33];
    int bx = blockIdx.x, by = blockIdx.y;
    int x = threadIdx.x & 31, y0 = threadIdx.x >> 5;
#pragma unroll
    for (int i = 0; i < 4; ++i) {
        int y = y0 + i * 8;
        tile[y][x] = W[(size_t)(by * 32 + y) * C + bx * 32 + x];
    }
    __syncthreads();
#pragma unroll
    for (int i = 0; i < 4; ++i) {
        int y = y0 + i * 8;
        Wt[(size_t)(bx * 32 + y) * R + by * 32 + x] = f2bf(tile[x][y]);
    }
}

// batched 768x768 transpose: z selects among 4 weight matrices
__global__ __launch_bounds__(256)
void transpose_cast4(const float* __restrict__ W0, const float* __restrict__ W1,
                     const float* __restrict__ W2, const float* __restrict__ W3,
                     u16* __restrict__ T0, u16* __restrict__ T1,
                     u16* __restrict__ T2, u16* __restrict__ T3) {
    const int z = blockIdx.z;
    const float* W = z == 0 ? W0 : z == 1 ? W1 : z == 2 ? W2 : W3;
    u16*         T = z == 0 ? T0 : z == 1 ? T1 : z == 2 ? T2 : T3;
    __shared__ float tile[32][33];
    int bx = blockIdx.x, by = blockIdx.y;
    int x = threadIdx.x & 31, y0 = threadIdx.x >> 5;
#pragma unroll
    for (int i = 0; i < 4; ++i) {
        int y = y0 + i * 8;
        tile[y][x] = W[(size_t)(by * 32 + y) * 768 + bx * 32 + x];
    }
    __syncthreads();
#pragma unroll
    for (int i = 0; i < 4; ++i) {
        int y = y0 + i * 8;
        T[(size_t)(bx * 32 + y) * 768 + by * 32 + x] = f2bf(tile[x][y]);
    }
}

// ---- mask (int 0/1): masked -> valid01 = 0 (float for V-zeroing, bf16 frag)
__global__ void maskprep(const int* __restrict__ m, float* __restrict__ vz,
                         u16* __restrict__ m01, int n) {
    int i = blockIdx.x * 256 + threadIdx.x;
    if (i < n) {
        float v = m[i] ? 0.0f : 1.0f;
        vz[i] = v;
        m01[i] = f2bf(v);
    }
}

// ---------------- LayerNorm fp32 -> bf16 (optionally skipped if iter==0) ----
__global__ __launch_bounds__(256)
void ln_bf16(const float* __restrict__ in, const float* __restrict__ g,
             const float* __restrict__ bta, u16* __restrict__ out,
             const int* __restrict__ iterp, int checkIter) {
    int row = blockIdx.x, tid = threadIdx.x;
    const float* x = in + (size_t)row * D_MODEL;
    float v0 = x[tid], v1 = x[tid + 256], v2 = x[tid + 512];
    float s = v0 + v1 + v2;
    float s2 = v0 * v0 + v1 * v1 + v2 * v2;
#pragma unroll
    for (int o = 1; o < 64; o <<= 1) { s += __shfl_xor(s, o); s2 += __shfl_xor(s2, o); }
    __shared__ float sh[8];
    int w = tid >> 6;
    if ((tid & 63) == 0) { sh[w] = s; sh[4 + w] = s2; }
    __syncthreads();
    s = sh[0] + sh[1] + sh[2] + sh[3];
    s2 = sh[4] + sh[5] + sh[6] + sh[7];
    float mu = s * (1.0f / 768.0f);
    float var = s2 * (1.0f / 768.0f) - mu * mu;
    float rstd = rsqrtf(var + 1e-6f);
    bool skip = checkIter && (iterp[0] == 0);
    u16* o0 = out + (size_t)row * D_MODEL;
    if (skip) {
        o0[tid] = f2bf(v0); o0[tid + 256] = f2bf(v1); o0[tid + 512] = f2bf(v2);
    } else {
        o0[tid]       = f2bf((v0 - mu) * rstd * g[tid]       + bta[tid]);
        o0[tid + 256] = f2bf((v1 - mu) * rstd * g[tid + 256] + bta[tid + 256]);
        o0[tid + 512] = f2bf((v2 - mu) * rstd * g[tid + 512] + bta[tid + 512]);
    }
}

// ------- fused split-K reduce + residual + LN2:  v = pf0+pf1+bias+res;
//         outm = v (fp32 residual); out = bf16(LN(v))
__global__ __launch_bounds__(256)
void ln_fuse(const float* __restrict__ pf, const float* __restrict__ bias,
             const float* __restrict__ res, const float* __restrict__ g,
             const float* __restrict__ bta, float* __restrict__ outm,
             u16* __restrict__ out) {
    int row = blockIdx.x, tid = threadIdx.x;
    size_t i0 = (size_t)row * D_MODEL + tid;
    const float* pf1 = pf + (size_t)MTOT * D_MODEL;
    float v0 = pf[i0]       + pf1[i0]       + bias[tid]       + res[i0];
    float v1 = pf[i0 + 256] + pf1[i0 + 256] + bias[tid + 256] + res[i0 + 256];
    float v2 = pf[i0 + 512] + pf1[i0 + 512] + bias[tid + 512] + res[i0 + 512];
    outm[i0] = v0; outm[i0 + 256] = v1; outm[i0 + 512] = v2;
    float s = v0 + v1 + v2;
    float s2 = v0 * v0 + v1 * v1 + v2 * v2;
#pragma unroll
    for (int o = 1; o < 64; o <<= 1) { s += __shfl_xor(s, o); s2 += __shfl_xor(s2, o); }
    __shared__ float sh[8];
    int w = tid >> 6;
    if ((tid & 63) == 0) { sh[w] = s; sh[4 + w] = s2; }
    __syncthreads();
    s = sh[0] + sh[1] + sh[2] + sh[3];
    s2 = sh[4] + sh[5] + sh[6] + sh[7];
    float mu = s * (1.0f / 768.0f);
    float var = s2 * (1.0f / 768.0f) - mu * mu;
    float rstd = rsqrtf(var + 1e-6f);
    u16* o0 = out + (size_t)row * D_MODEL;
    o0[tid]       = f2bf((v0 - mu) * rstd * g[tid]       + bta[tid]);
    o0[tid + 256] = f2bf((v1 - mu) * rstd * g[tid + 256] + bta[tid + 256]);
    o0[tid + 512] = f2bf((v2 - mu) * rstd * g[tid + 512] + bta[tid + 512]);
}

// ---------------- GEMM  C = A[M][K] * Bt[N][K]^T  (bf16 in, fp32 acc) -------
// 128x128 tile, BK=32, ring-3 LDS, XCD-aware bijective block swizzle (T1):
// physical wg P runs logical tile wgid = (P%8)*(nwg/8) + P/8, so each XCD's
// contiguous logical chunk (bn-fastest) keeps A-row-panels on ONE XCD L2
// (was ~8x HBM re-fetch: FETCH 83 MB vs ~11 MB ideal on FFN1, R16 profile).
// Requires nwg % 8 == 0 (all launches satisfy this).
template <int MODE>
__global__ __launch_bounds__(256, 3)
void gemm_bt(const u16* __restrict__ A, const u16* __restrict__ Bt,
             int K, int N,
             const float* __restrict__ bias0, const float* __restrict__ bias1,
             const float* __restrict__ bias2,
             const float* __restrict__ res,
             float* __restrict__ outF, u16* __restrict__ oq,
             u16* __restrict__ ok, u16* __restrict__ ov) {
    __shared__ __align__(16) u16 aT[3][128 * 32];
    __shared__ __align__(16) u16 bT[3][128 * 32];
    const int tid = threadIdx.x;
    const int lane = tid & 63;
    const int w = tid >> 6;
    const int wr = w >> 1, wc = w & 1;
    const int lm = lane & 15, lq = lane >> 4;

    // XCD-aware swizzle: contiguous logical chunk per XCD
    const int gx = gridDim.x, gy = gridDim.y;
    const int nwg = gx * gy * gridDim.z;
    const int orig = (blockIdx.z * gy + blockIdx.y) * gx + blockIdx.x;
    const int wgid = (orig & 7) * (nwg >> 3) + (orig >> 3);
    const int bn = wgid % gx;
    const int tmp = wgid / gx;
    const int bm = tmp % gy;
    const int bz = tmp / gy;

    const int kzlen = K / gridDim.z;
    const int kbeg = bz * kzlen;
    const int nsteps = kzlen >> 5;

    const u16* Abase = A  + (size_t)(bm * 128) * K + kbeg;
    const u16* Bbase = Bt + (size_t)(bn * 128) * K + kbeg;

    auto stage = [&](int buf, int t) {
        int k0 = t * 32;
#pragma unroll
        for (int j = 0; j < 2; ++j) {
            int d = j * 256 + tid;          // 16B-chunk index within tile
            int row = d >> 2, p = d & 3;
            int src = (p ^ (row & 3)) * 8;
            gload16(Abase + (size_t)row * K + k0 + src, aT[buf] + (j * 256 + w * 64) * 8);
            gload16(Bbase + (size_t)row * K + k0 + src, bT[buf] + (j * 256 + w * 64) * 8);
        }
    };

    f32x4 acc[4][4] = {};
    stage(0, 0);
    if (nsteps > 1) stage(1, 1);

#pragma unroll 1
    for (int t = 0; t < nsteps; ++t) {
        if (t + 1 < nsteps) asm volatile("s_waitcnt vmcnt(4)" ::: "memory");
        else                asm volatile("s_waitcnt vmcnt(0)" ::: "memory");
        __syncthreads();
        const u16* Ab = aT[t % 3];
        const u16* Bb = bT[t % 3];
        short8 av[4], bv[4];
#pragma unroll
        for (int m = 0; m < 4; ++m) {
            int row = wr * 64 + m * 16 + lm;
            av[m] = *(const short8*)(Ab + row * 32 + ((lq ^ (row & 3)) * 8));
        }
#pragma unroll
        for (int n = 0; n < 4; ++n) {
            int row = wc * 64 + n * 16 + lm;
            bv[n] = *(const short8*)(Bb + row * 32 + ((lq ^ (row & 3)) * 8));
        }
#pragma unroll
        for (int m = 0; m < 4; ++m)
#pragma unroll
            for (int n = 0; n < 4; ++n)
                acc[m][n] = MFMA16(av[m], bv[n], acc[m][n]);
        if (t + 2 < nsteps) stage((t + 2) % 3, t + 2);   // refill ring
    }

#pragma unroll
    for (int m = 0; m < 4; ++m) {
#pragma unroll
        for (int n = 0; n < 4; ++n) {
            int col = bn * 128 + wc * 64 + n * 16 + lm;
#pragma unroll
            for (int r = 0; r < 4; ++r) {
                int row = bm * 128 + wr * 64 + m * 16 + lq * 4 + r;
                float v = acc[m][n][r];
                if (MODE == 0) {
                    int proj = col / D_MODEL;
                    int d = col - proj * D_MODEL;
                    int hh = d >> 6, dhi = d & 63;
                    int bb = row >> 11, sIdx = row & 2047;
                    if (proj == 0) {
                        v = (v + bias0[d]) * 0.18033688011112042f;
                        oq[((size_t)(bb * HEADS + hh) * SS + sIdx) * DHEAD + dhi] = f2bf(v);
                    } else if (proj == 1) {
                        v = v + bias1[d];
                        ok[((size_t)(bb * HEADS + hh) * SS + sIdx) * DHEAD + dhi] = f2bf(v);
                    } else {
                        v = (v + bias2[d]) * res[row];
                        ov[((size_t)(bb * HEADS + hh) * DHEAD + dhi) * SS + sIdx] = f2bf(v);
                    }
                } else if (MODE == 1) {
                    if (gridDim.z > 1) {
                        outF[((size_t)bz * MTOT + row) * N + col] = v;
                    } else {
                        size_t idx = (size_t)row * N + col;
                        outF[idx] = v + bias0[col] + res[idx];
                    }
                } else if (MODE == 2) {
                    float t2 = v + bias0[col];
                    oq[(size_t)row * N + col] = f2bf(gelu_tanh_f(t2));
                } else {   // MODE 3: raw bf16 partial
                    oq[((size_t)bz * MTOT + row) * N + col] = f2bf(v);
                }
            }
        }
    }
}

// ---------------- QKV split-K reduce + epilogue scatter ---------------------
// P = bf16 partials [2][MTOT][2304]. Zones (blockIdx.y): 0=q, 1=k, 2=v^T.
__global__ __launch_bounds__(256)
void reduce_qkv(const u16* __restrict__ P,
                const float* __restrict__ bq, const float* __restrict__ bk,
                const float* __restrict__ bv, const float* __restrict__ vz,
                u16* __restrict__ qq, u16* __restrict__ kk,
                u16* __restrict__ vt) {
    const int zone = blockIdx.y;
    const int tid = threadIdx.x;
    const u16* P1 = P + (size_t)MTOT * 2304;

    if (zone < 2) {
        // thread handles 8 consecutive cols of one row; 16B loads/stores
        int idx = blockIdx.x * 256 + tid;            // < 4096*96
        int row = idx / 96;
        int c8  = idx - row * 96;
        int col = zone * 768 + c8 * 8;
        short8 a = *(const short8*)(P  + (size_t)row * 2304 + col);
        short8 b = *(const short8*)(P1 + (size_t)row * 2304 + col);
        const float* bias = zone ? bk : bq;
        union { u16 u[8]; short8 s; } o;
#pragma unroll
        for (int e = 0; e < 8; ++e) {
            float v = bf2f((u16)a[e]) + bf2f((u16)b[e]) + bias[c8 * 8 + e];
            if (zone == 0) v *= 0.18033688011112042f;   // 1/8 * log2(e)
            o.u[e] = f2bf(v);
        }
        int d = c8 * 8, hh = d >> 6, dhi = d & 63;
        int bb = row >> 11, s = row & 2047;
        u16* dst = (zone ? kk : qq) +
                   ((size_t)(bb * HEADS + hh) * SS + s) * DHEAD + dhi;
        *(short8*)dst = o.s;
    } else {
        // v^T via LDS transpose: 64x64 tile of (row, vcol) space
        if (blockIdx.x >= 768) return;               // 64 row-tiles x 12 heads
        __shared__ u16 tile[64][72];
        int tr = blockIdx.x / 12, tc = blockIdx.x - tr * 12;
        int r0 = tr * 64;
#pragma unroll
        for (int p = 0; p < 2; ++p) {
            int lr = p * 32 + (tid >> 3);            // 0..63 local row
            int coff = (tid & 7) * 8;
            int row = r0 + lr;
            const u16* p0 = P + (size_t)row * 2304 + 1536 + tc * 64 + coff;
            short8 a = *(const short8*)p0;
            short8 b = *(const short8*)(p0 + (size_t)MTOT * 2304);
            float zf = vz[row];
#pragma unroll
            for (int e = 0; e < 8; ++e) {
                float v = (bf2f((u16)a[e]) + bf2f((u16)b[e]) +
                           bv[tc * 64 + coff + e]) * zf;
                tile[lr][coff + e] = f2bf(v);
            }
        }
        __syncthreads();
        int c = tid >> 2, sg = tid & 3;              // c: dhi, sg: 16-row group
        union { u16 u[16]; f32x4 v4[4]; } buf;
#pragma unroll
        for (int i = 0; i < 16; ++i) buf.u[i] = tile[sg * 16 + i][c];
        int bb = r0 >> 11;
        int s0 = (r0 & 2047) + sg * 16;
        u16* dst = vt + ((size_t)(bb * HEADS + tc) * DHEAD + c) * SS + s0;
        *(f32x4*)dst = buf.v4[0];
        *(f32x4*)(dst + 8) = buf.v4[1];
    }
}

// ---------------- split-K=2 reduce: out = pf[0] + pf[1] + bias + res --------
__global__ __launch_bounds__(256)
void reduce_ks2(const float* __restrict__ pf, const float* __restrict__ bias,
                const float* __restrict__ res, float* __restrict__ out, int N) {
    size_t i = ((size_t)blockIdx.x * 256 + threadIdx.x) * 4;
    f32x4 s0 = *(const f32x4*)(pf + i);
    f32x4 s1 = *(const f32x4*)(pf + (size_t)MTOT * N + i);
    int col = (int)(i % (size_t)N);
    f32x4 b = *(const f32x4*)(bias + col);
    f32x4 r = *(const f32x4*)(res + i);
    f32x4 o;
#pragma unroll
    for (int e = 0; e < 4; ++e) o[e] = s0[e] + s1[e] + b[e] + r[e];
    *(f32x4*)(out + i) = o;
}

// ---------------- flash attention: 4-wave + ring-3 --------------------------
// Max-free softmax; V rows pre-zeroed for masked keys; l = MFMA(mask01, P).
template <int NCH>
__global__ __launch_bounds__(256, 3)
void attn_fwd6(const u16* __restrict__ q, const u16* __restrict__ k,
               const u16* __restrict__ vtg, const u16* __restrict__ m01g,
               u16* __restrict__ po, float* __restrict__ pml) {
    constexpr int KLEN = SS / NCH;      // keys per chunk
    constexpr int KT   = KLEN / 64;     // 64-key tiles per chunk
    __shared__ __align__(16) u16 kls[3][64 * 64];   // [key][d], XOR-swizzled
    __shared__ __align__(16) u16 vls[3][64 * 64];   // [d][key], XOR-swizzled
    __shared__ __align__(16) u16 m01l[KLEN];        // valid01 bf16 chunk

    const int tid = threadIdx.x, lane = tid & 63, w = tid >> 6;
    const int lm = lane & 31, hi = lane >> 5;
    const int head = blockIdx.y;
    const int qblk = blockIdx.x / NCH, chunk = blockIdx.x % NCH;
    const int q0 = qblk * 128;
    const int k0 = chunk * KLEN;

    const u16* qbase = q + (size_t)head * SS * DHEAD;
    const u16* kbase = k + (size_t)head * SS * DHEAD;
    const u16* vbase = vtg + (size_t)head * DHEAD * SS;
    const u16* m01row = m01g + (head / HEADS) * SS;

    short8 qf[4];
    const int qrow = q0 + w * 32 + lm;
#pragma unroll
    for (int c = 0; c < 4; ++c)
        qf[c] = *(const short8*)(qbase + (size_t)qrow * DHEAD + c * 16 + hi * 8);

    if (tid < KLEN / 8)
        gload16(m01row + k0 + (size_t)tid * 8, m01l + (size_t)(tid >> 6) * 64 * 8);

    auto stage = [&](int buf, int t) {
#pragma unroll
        for (int j = 0; j < 2; ++j) {
            int c = j * 256 + tid;
            int row = c >> 3, jj = c & 7;
            gload16(kbase + (size_t)(k0 + t * 64 + row) * DHEAD + ((jj ^ (row & 7)) * 8),
                    kls[buf] + (j * 256 + w * 64) * 8);
            gload16(vbase + (size_t)row * SS + k0 + t * 64 + ((jj ^ (row & 7)) * 8),
                    vls[buf] + (j * 256 + w * 64) * 8);
        }
    };
    stage(0, 0);
    if (KT > 1) stage(1, 1);

    f32x16 o0 = {}, o1 = {}, accl = {};

#pragma unroll 1
    for (int t = 0; t < KT; ++t) {
        if (t + 1 < KT) asm volatile("s_waitcnt vmcnt(4)" ::: "memory");
        else            asm volatile("s_waitcnt vmcnt(0)" ::: "memory");
        __syncthreads();
        const u16* kb = kls[t % 3];
        const u16* vb = vls[t % 3];
#pragma unroll
        for (int s = 0; s < 2; ++s) {
            short8 av[4];
#pragma unroll
            for (int c = 0; c < 4; ++c)
                av[c] = *(const short8*)(kb + (s * 32 + lm) * 64 + (((c * 2 + hi) ^ (lm & 7)) * 8));
            short8 vf[4];
#pragma unroll
            for (int kc = 0; kc < 2; ++kc)
#pragma unroll
                for (int df = 0; df < 2; ++df)
                    vf[kc * 2 + df] = *(const short8*)(vb + (df * 32 + lm) * 64 +
                                                       (((s * 4 + kc * 2 + hi) ^ (lm & 7)) * 8));
            short8 mf0 = *(const short8*)(m01l + t * 64 + s * 32 + hi * 8);
            short8 mf1 = *(const short8*)(m01l + t * 64 + s * 32 + 16 + hi * 8);

            f32x16 st = {};
#pragma unroll
            for (int c = 0; c < 4; ++c) st = MFMA32(av[c], qf[c], st);

            float p[16];
#pragma unroll
            for (int r = 0; r < 16; ++r) p[r] = exp2_fast(st[r]);

            u32 W[8];
#pragma unroll
            for (int t8 = 0; t8 < 8; ++t8) W[t8] = cvtpk(p[2 * t8], p[2 * t8 + 1]);
            union { u32 wd[4]; short8 s8; } pf0, pf1;
            u32 a0w = W[0], b0w = W[2]; plswap(a0w, b0w, hi);
            u32 a1w = W[1], b1w = W[3]; plswap(a1w, b1w, hi);
            u32 a2w = W[4], b2w = W[6]; plswap(a2w, b2w, hi);
            u32 a3w = W[5], b3w = W[7]; plswap(a3w, b3w, hi);
            pf0.wd[0] = a0w; pf0.wd[1] = a1w; pf0.wd[2] = b0w; pf0.wd[3] = b1w;
            pf1.wd[0] = a2w; pf1.wd[1] = a3w; pf1.wd[2] = b2w; pf1.wd[3] = b3w;

            accl = MFMA32(mf0, pf0.s8, accl);
            accl = MFMA32(mf1, pf1.s8, accl);
            o0 = MFMA32(vf[0], pf0.s8, o0);
            o1 = MFMA32(vf[1], pf0.s8, o1);
            o0 = MFMA32(vf[2], pf1.s8, o0);
            o1 = MFMA32(vf[3], pf1.s8, o1);
        }
        if (t + 2 < KT) stage((t + 2) % 3, t + 2);
    }

    const int pc = (head * 16 + qblk) * NCH + chunk;
    u16* orow = po + ((size_t)pc * 128 + (w * 32 + lm)) * 64;
#pragma unroll
    for (int g = 0; g < 4; ++g) {
        short4v pk0, pk1;
#pragma unroll
        for (int e = 0; e < 4; ++e) {
            pk0[e] = (short)f2bf(o0[g * 4 + e]);
            pk1[e] = (short)f2bf(o1[g * 4 + e]);
        }
        *(short4v*)(orow + g * 8 + hi * 4) = pk0;
        *(short4v*)(orow + 32 + g * 8 + hi * 4) = pk1;
    }
    if (hi == 0)
        pml[(size_t)pc * 128 + (w * 32 + lm)] = accl[0];
}

// ---------------- merge split-K partials -> ctx bf16 [B,S,H*64] ------------
__global__ __launch_bounds__(256)
void attn_merge(const u16* __restrict__ po, const float* __restrict__ pml,
                u16* __restrict__ ctx, int nch) {
    const int head = blockIdx.y;
    const int bb = head / HEADS, hh = head % HEADS;
    const int rl = threadIdx.x >> 4, dg = threadIdx.x & 15;
    const int s = blockIdx.x * 16 + rl;
    const int qb = s >> 7, qr = s & 127;
    const int pcb = (head * 16 + qb) * nch;

    float denom = 0.0f;
    float acc[4] = {0.0f, 0.0f, 0.0f, 0.0f};
#pragma unroll 4
    for (int c = 0; c < nch; ++c) {
        denom += pml[((size_t)(pcb + c)) * 128 + qr];
        const u16* op = po + (((size_t)(pcb + c) * 128 + qr) * 64) + dg * 4;
        short4v a = *(const short4v*)op;
#pragma unroll
        for (int e = 0; e < 4; ++e) acc[e] += bf2f((u16)a[e]);
    }
    float inv = 1.0f / denom;
    short4v r;
#pragma unroll
    for (int e = 0; e < 4; ++e) r[e] = (short)f2bf(acc[e] * inv);
    *(short4v*)(ctx + ((size_t)(bb * SS + s)) * D_MODEL + hh * DHEAD + dg * 4) = r;
}

// ---------------------------------------------------------------------------
extern "C" void kernel_launch(void* const* d_in, const int* in_sizes, int n_in,
                              void* d_out, int out_size, void* d_ws, size_t ws_size,
                              hipStream_t stream) {
    const int*   iterp  = (const int*)  d_in[0];
    const float* inputs = (const float*)d_in[2];
    const int*   mask   = (const int*)  d_in[3];
    const float* Wq = (const float*)d_in[4];
    const float* bq = (const float*)d_in[5];
    const float* Wk = (const float*)d_in[6];
    const float* bk = (const float*)d_in[7];
    const float* Wv = (const float*)d_in[8];
    const float* bv = (const float*)d_in[9];
    const float* Wo = (const float*)d_in[10];
    const float* bo = (const float*)d_in[11];
    const float* ln1g = (const float*)d_in[12];
    const float* ln1b = (const float*)d_in[13];
    const float* W1 = (const float*)d_in[14];
    const float* b1 = (const float*)d_in[15];
    const float* W2 = (const float*)d_in[16];
    const float* b2 = (const float*)d_in[17];
    const float* ln2g = (const float*)d_in[18];
    const float* ln2b = (const float*)d_in[19];
    float* outp = (float*)d_out;

    char* ws = (char*)d_ws;
    size_t off = 0;
    auto alloc = [&](size_t bytes) -> void* {
        void* p = ws + off;
        off += (bytes + 255) & ~(size_t)255;
        return p;
    };
    u16*   wqkv_t = (u16*)  alloc((size_t)2304 * 768 * 2);
    u16*   wo_t   = (u16*)  alloc((size_t)768 * 768 * 2);
    u16*   w1_t   = (u16*)  alloc((size_t)3072 * 768 * 2);
    u16*   w2_t   = (u16*)  alloc((size_t)768 * 3072 * 2);
    float* vzf    = (float*)alloc((size_t)MTOT * 4);        // valid01 fp32
    u16*   m01    = (u16*)  alloc((size_t)MTOT * 2);        // valid01 bf16
    u16*   xh     = (u16*)  alloc((size_t)MTOT * 768 * 2);  // x / h / attn l
    u16*   qb     = (u16*)  alloc((size_t)MTOT * 768 * 2);
    u16*   kbuf   = (u16*)  alloc((size_t)MTOT * 768 * 2);
    u16*   vtb    = (u16*)  alloc((size_t)MTOT * 768 * 2);
    u16*   ctxb   = (u16*)  alloc((size_t)MTOT * 768 * 2);
    float* outm   = (float*)alloc((size_t)MTOT * 768 * 4);  // 12.58 MB
    u16*   inter  = qb;  // reuse q|k|vt|ctx region

    // fp32 split-K partial buffer for the skinny GEMMs (Wo, FFN2): 25.2 MB.
    // Allocated right after outm -> contiguous 37.8 MB span = QKV bf16 P.
    float* pfbuf = (float*)alloc((size_t)2 * MTOT * 768 * 4);
    const bool split_ok = (off <= ws_size);   // fallback if ws too small

    float* pml = (float*)xh;

    dim3 blk(256);
    transpose_cast4<<<dim3(24, 24, 4), blk, 0, stream>>>(
        Wq, Wk, Wv, Wo,
        wqkv_t, wqkv_t + 768 * 768, wqkv_t + 2 * 768 * 768, wo_t);
    transpose_cast<<<dim3(96, 24), blk, 0, stream>>>(W1, w1_t, 768, 3072);
    transpose_cast<<<dim3(24, 96), blk, 0, stream>>>(W2, w2_t, 3072, 768);
    maskprep<<<dim3(16), blk, 0, stream>>>(mask, vzf, m01, MTOT);

    // x = LN1(inputs) (skipped if iter==0), bf16
    ln_bf16<<<dim3(MTOT), blk, 0, stream>>>(inputs, ln1g, ln1b, xh, iterp, 1);

    // fused QKV projection — split-K=2 (grid 1152, %8==0)
    if (split_ok) {
        u16* P = (u16*)outm;
        gemm_bt<3><<<dim3(2304 / 128, MTOT / 128, 2), blk, 0, stream>>>(
            xh, wqkv_t, 768, 2304, nullptr, nullptr, nullptr, nullptr,
            nullptr, P, nullptr, nullptr);
        reduce_qkv<<<dim3(1536, 3), blk, 0, stream>>>(
            P, bq, bk, bv, vzf, qb, kbuf, vtb);
    } else {
        gemm_bt<0><<<dim3(2304 / 128, MTOT / 128), blk, 0, stream>>>(
            xh, wqkv_t, 768, 2304, bq, bk, bv, vzf, nullptr, qb, kbuf, vtb);
    }

    // flash attention: 4-wave blocks, ring-3, split-K=4
    if (split_ok) {
        u16* po = (u16*)pfbuf;
        attn_fwd6<4><<<dim3(16 * 4, BB * HEADS), blk, 0, stream>>>(
            qb, kbuf, vtb, m01, po, pml);
        attn_merge<<<dim3(SS / 16, BB * HEADS), blk, 0, stream>>>(po, pml, ctxb, 4);
    } else {
        u16* po = (u16*)outm;
        attn_fwd6<2><<<dim3(16 * 2, BB * HEADS), blk, 0, stream>>>(
            qb, kbuf, vtb, m01, po, pml);
        attn_merge<<<dim3(SS / 16, BB * HEADS), blk, 0, stream>>>(po, pml, ctxb, 2);
    }

    // out = ctx @ Wo + bo + inputs; h = LN2(out)
    if (split_ok) {
        gemm_bt<1><<<dim3(768 / 128, MTOT / 128, 2), blk, 0, stream>>>(
            ctxb, wo_t, 768, 768, nullptr, nullptr, nullptr, nullptr,
            pfbuf, nullptr, nullptr, nullptr);
        ln_fuse<<<dim3(MTOT), blk, 0, stream>>>(pfbuf, bo, inputs, ln2g, ln2b, outm, xh);
    } else {
        gemm_bt<1><<<dim3(768 / 128, MTOT / 128), blk, 0, stream>>>(
            ctxb, wo_t, 768, 768, bo, nullptr, nullptr, inputs, outm, nullptr, nullptr, nullptr);
        ln_bf16<<<dim3(MTOT), blk, 0, stream>>>(outm, ln2g, ln2b, xh, iterp, 0);
    }

    // inter = gelu(h @ W1 + b1), bf16  (768 blocks, %8==0)
    gemm_bt<2><<<dim3(3072 / 128, MTOT / 128), blk, 0, stream>>>(
        xh, w1_t, 768, 3072, b1, nullptr, nullptr, nullptr, nullptr, inter, nullptr, nullptr);

    // d_out = inter @ W2 + b2 + out  (fp32)  — split-K=2 -> 384 blocks
    if (split_ok) {
        gemm_bt<1><<<dim3(768 / 128, MTOT / 128, 2), blk, 0, stream>>>(
            inter, w2_t, 3072, 768, nullptr, nullptr, nullptr, nullptr,
            pfbuf, nullptr, nullptr, nullptr);
        reduce_ks2<<<dim3(MTOT * 768 / 1024), blk, 0, stream>>>(pfbuf, b2, outm, outp, 768);
    } else {
        gemm_bt<1><<<dim3(768 / 128, MTOT / 128), blk, 0, stream>>>(
            inter, w2_t, 3072, 768, b2, nullptr, nullptr, outm, outp, nullptr, nullptr, nullptr);
    }
}